// Round 1
// baseline (2242.164 us; speedup 1.0000x reference)
//
#include <hip/hip_runtime.h>

#define DEV static __device__ __forceinline__

namespace {
constexpr int PB   = 4096;      // points per batch
constexpr int NPTS = 32768;     // B*P
constexpr int RR   = 8;
constexpr int K    = 16;        // 2*r
constexpr int COUT = 128;
constexpr int MID  = 32;
constexpr int NK   = NPTS * K;  // 524288 rows
constexpr float BN_EPS = 1e-5f;

// ws float offsets
constexpr int WS_SUM1 = 0;      // 4:  s0,s1,q0,q1
constexpr int WS_SUM2 = 4;      // 64: s[32], q[32]
constexpr int WS_SUM3 = 68;     // 8:  s[4], q[4]
constexpr int WS_PAR1 = 80;     // 4:  sc[2], sh[2]
constexpr int WS_PAR2 = 84;     // 64: sc[32], sh[32]
constexpr int WS_PAR3 = 148;    // 8:  sc[4], sh[4]
constexpr size_t WS_ENERGY = 256;                       // NK*16 floats
constexpr size_t WS_W2     = WS_ENERGY + (size_t)NK * 16; // NK*4 floats
}

DEV int nbr_idx(int n, int j) {
    int b = n >> 12, i = n & (PB - 1);
    int o = (j < RR) ? (j - RR) : (j - RR + 1);
    return (b << 12) | ((i + o + PB) & (PB - 1));
}
DEV float dot4(float4 a, float4 b) { return a.x*b.x + a.y*b.y + a.z*b.z + a.w*b.w; }
DEV float wave_sum(float v) {
    #pragma unroll
    for (int off = 32; off >= 1; off >>= 1) v += __shfl_xor(v, off);
    return v;
}

// ---------------- stage 1: trans/idx, BN1 sums, e, energy ----------------
__global__ __launch_bounds__(256) void k_stage1(
    const float* __restrict__ pts, const float* __restrict__ feat,
    const float* __restrict__ W1, const float* __restrict__ b1,
    const float* __restrict__ Wb, const float* __restrict__ bb,
    const float* __restrict__ Wp1,
    float* __restrict__ out_trans, float* __restrict__ out_idx,
    float* __restrict__ ws)
{
    __shared__ float  W1t[K * 2];
    __shared__ float4 W1f[K * 16];
    __shared__ float  b1s[K], bbs[K];
    __shared__ float4 Wbs[K * K * 4];
    __shared__ float  red[4][4];

    const int t = threadIdx.x;
    const float4* Wb4 = reinterpret_cast<const float4*>(Wb);
    for (int x = t; x < K * K * 4; x += 256) Wbs[x] = Wb4[x];
    for (int x = t; x < K * 16; x += 256) {
        int o = x >> 4, m = x & 15;
        const float* w = W1 + o * 66 + 2 + m * 4;
        W1f[x] = make_float4(w[0], w[1], w[2], w[3]);
    }
    if (t < K * 2) W1t[t] = W1[(t >> 1) * 66 + (t & 1)];
    if (t < K) { b1s[t] = b1[t]; bbs[t] = bb[t]; }
    __syncthreads();

    const int row = blockIdx.x * 256 + t;
    const int n = row >> 4, j = row & 15;
    const int idxr = nbr_idx(n, j);
    const float tx = pts[2 * idxr]     - pts[2 * n];
    const float ty = pts[2 * idxr + 1] - pts[2 * n + 1];
    reinterpret_cast<float2*>(out_trans)[row] = make_float2(tx, ty);
    out_idx[row] = (float)idxr;

    // BN1 partial sums on p1 = trans @ Wp1^T
    {
        const float p10 = Wp1[0] * tx + Wp1[1] * ty;
        const float p11 = Wp1[2] * tx + Wp1[3] * ty;
        float v[4] = {p10, p11, p10 * p10, p11 * p11};
        #pragma unroll
        for (int q = 0; q < 4; ++q) {
            float s = wave_sum(v[q]);
            if ((t & 63) == 0) red[t >> 6][q] = s;
        }
        __syncthreads();
        if (t < 4) atomicAdd(&ws[WS_SUM1 + t], red[0][t] + red[1][t] + red[2][t] + red[3][t]);
    }

    float4 f4[16];
    const float4* fr = reinterpret_cast<const float4*>(feat) + (size_t)idxr * 16;
    #pragma unroll
    for (int m = 0; m < 16; ++m) f4[m] = fr[m];

    float e[K];
    #pragma unroll
    for (int o = 0; o < K; ++o) {
        float acc = b1s[o] + W1t[2 * o] * tx + W1t[2 * o + 1] * ty;
        #pragma unroll
        for (int m = 0; m < 16; ++m) acc += dot4(W1f[o * 16 + m], f4[m]);
        e[o] = fmaxf(acc, 0.f);
    }
    float4 e4[4];
    #pragma unroll
    for (int q = 0; q < 4; ++q) e4[q] = make_float4(e[4*q], e[4*q+1], e[4*q+2], e[4*q+3]);

    float* erow = ws + WS_ENERGY + (size_t)row * 16;
    for (int o = 0; o < K; ++o) {          // dynamic loop: keeps code size sane
        float acc = bbs[o];
        #pragma unroll
        for (int i = 0; i < K; ++i) {
            float u = 0.f;
            #pragma unroll
            for (int q = 0; q < 4; ++q) u += dot4(Wbs[(o * 16 + i) * 4 + q], e4[q]);
            acc = fmaf(e[i], u, acc);
        }
        erow[o] = acc;
    }
}

// ---------------- BN finalize: sums -> scale/shift ----------------
__global__ void k_finalize(const float* __restrict__ g, const float* __restrict__ b,
                           float* __restrict__ ws, int sum_off, int par_off, int nch)
{
    int c = threadIdx.x;
    if (c >= nch) return;
    const float invM = 1.f / (float)NK;
    float m = ws[sum_off + c] * invM;
    float q = ws[sum_off + nch + c] * invM;
    float rs = rsqrtf(q - m * m + BN_EPS);
    float sc = g[c] * rs;
    ws[par_off + c] = sc;
    ws[par_off + nch + c] = fmaf(-m, sc, b[c]);
}

// ---------------- stages 2 & 3 (shared body) ----------------
template <int STAGE>
__global__ __launch_bounds__(256) void k_stage23(
    const float* __restrict__ Wp1, const float* __restrict__ Wp2,
    const float* __restrict__ bp2, const float* __restrict__ W2a,
    const float* __restrict__ W2b,
    const float* __restrict__ out_trans, float* __restrict__ ws)
{
    __shared__ float4 Wp2s[64];
    __shared__ float  bp2s[COUT];
    __shared__ float4 W2as[MID * 8];
    __shared__ float  W2bs[4 * MID];
    __shared__ float  bn2p[64];
    __shared__ float  red[4][64];

    const int t = threadIdx.x;
    for (int x = t; x < 64; x += 256) Wp2s[x] = reinterpret_cast<const float4*>(Wp2)[x];
    for (int x = t; x < COUT; x += 256) bp2s[x] = bp2[x];
    for (int x = t; x < MID * 8; x += 256) W2as[x] = reinterpret_cast<const float4*>(W2a)[x];
    if (STAGE == 3) {
        for (int x = t; x < 4 * MID; x += 256) W2bs[x] = W2b[x];
        for (int x = t; x < 64; x += 256) bn2p[x] = ws[WS_PAR2 + x];
    }
    __syncthreads();

    const float sc10 = ws[WS_PAR1 + 0], sc11 = ws[WS_PAR1 + 1];
    const float sh10 = ws[WS_PAR1 + 2], sh11 = ws[WS_PAR1 + 3];
    const float wp10 = Wp1[0], wp11 = Wp1[1], wp12 = Wp1[2], wp13 = Wp1[3];

    constexpr int NA = (STAGE == 2) ? 32 : 4;
    float s1a[NA], s2a[NA];
    #pragma unroll
    for (int q = 0; q < NA; ++q) { s1a[q] = 0.f; s2a[q] = 0.f; }

    const int stride = gridDim.x * 256;
    for (int row = blockIdx.x * 256 + t; row < NK; row += stride) {
        const float2 tr = reinterpret_cast<const float2*>(out_trans)[row];
        const float p10 = wp10 * tr.x + wp11 * tr.y;
        const float p11 = wp12 * tr.x + wp13 * tr.y;
        const float ph0 = fmaxf(fmaf(p10, sc10, sh10), 0.f);
        const float ph1 = fmaxf(fmaf(p11, sc11, sh11), 0.f);

        // shrink[j2] = sum_a p_embed[a*16+j2]
        float4 sh4[4];
        #pragma unroll
        for (int jq = 0; jq < 4; ++jq) {
            float v[4];
            #pragma unroll
            for (int jj = 0; jj < 4; ++jj) {
                const int j2 = jq * 4 + jj;
                float a = 0.f;
                #pragma unroll
                for (int a8 = 0; a8 < 8; ++a8) {
                    const int c = a8 * 16 + j2;
                    float4 wv = Wp2s[c >> 1];
                    const float w0 = (j2 & 1) ? wv.z : wv.x;
                    const float w1 = (j2 & 1) ? wv.w : wv.y;
                    a += ph0 * w0 + ph1 * w1 + bp2s[c];
                }
                v[jj] = a;
            }
            sh4[jq] = make_float4(v[0], v[1], v[2], v[3]);
        }

        float4 en4[4];
        const float4* ep = reinterpret_cast<const float4*>(ws + WS_ENERGY) + (size_t)row * 4;
        #pragma unroll
        for (int q = 0; q < 4; ++q) en4[q] = ep[q];

        float w2acc[4] = {0.f, 0.f, 0.f, 0.f};
        #pragma unroll
        for (int q = 0; q < MID; ++q) {
            float acc = 0.f;
            #pragma unroll
            for (int c = 0; c < 4; ++c) acc += dot4(W2as[q * 8 + c], en4[c]);
            #pragma unroll
            for (int c = 0; c < 4; ++c) acc += dot4(W2as[q * 8 + 4 + c], sh4[c]);
            if (STAGE == 2) {
                s1a[q] += acc;
                s2a[q] += acc * acc;
            } else {
                const float h = fmaxf(fmaf(acc, bn2p[q], bn2p[32 + q]), 0.f);
                #pragma unroll
                for (int p = 0; p < 4; ++p) w2acc[p] = fmaf(W2bs[p * MID + q], h, w2acc[p]);
            }
        }
        if (STAGE == 3) {
            #pragma unroll
            for (int p = 0; p < 4; ++p) { s1a[p] += w2acc[p]; s2a[p] += w2acc[p] * w2acc[p]; }
            reinterpret_cast<float4*>(ws + WS_W2)[row] =
                make_float4(w2acc[0], w2acc[1], w2acc[2], w2acc[3]);
        }
    }

    const int w = t >> 6, lane = t & 63;
    const int sum_off = (STAGE == 2) ? WS_SUM2 : WS_SUM3;
    #pragma unroll
    for (int q = 0; q < NA; ++q) {
        float v = wave_sum(s1a[q]);
        if (lane == 0) red[w][q] = v;
        v = wave_sum(s2a[q]);
        if (lane == 0) red[w][NA + q] = v;
    }
    __syncthreads();
    if (t < 2 * NA) atomicAdd(&ws[sum_off + t], red[0][t] + red[1][t] + red[2][t] + red[3][t]);
}

// ---------------- stage 4: softmax weights + v-matmul + combine ----------------
__global__ __launch_bounds__(256) void k_stage4(
    const float* __restrict__ feat, const float* __restrict__ Wp1,
    const float* __restrict__ Wp2, const float* __restrict__ bp2,
    const float* __restrict__ W2c, const float* __restrict__ b2c,
    const float* __restrict__ W3, const float* __restrict__ b3,
    const float* __restrict__ out_trans, const float* __restrict__ ws,
    float* __restrict__ out)
{
    __shared__ float4 W3s[COUT * 17];    // [cout][16 float4 + 1 pad]
    __shared__ float4 fbuf[4][K * 17];   // per-wave gathered features
    __shared__ float  smw[4][K][17];     // softmax logits
    __shared__ float4 Wp2s[64];
    __shared__ float  bp2s[COUT], b3s[COUT], W2cs[64], b2cs[K];

    const int t = threadIdx.x;
    const float4* W34 = reinterpret_cast<const float4*>(W3);
    for (int x = t; x < COUT * 16; x += 256) W3s[(x >> 4) * 17 + (x & 15)] = W34[x];
    for (int x = t; x < 64; x += 256) Wp2s[x] = reinterpret_cast<const float4*>(Wp2)[x];
    for (int x = t; x < COUT; x += 256) { bp2s[x] = bp2[x]; b3s[x] = b3[x]; }
    for (int x = t; x < 64; x += 256) W2cs[x] = W2c[x];
    if (t < K) b2cs[t] = b2c[t];
    __syncthreads();

    const int w = t >> 6, lane = t & 63;
    const int c0 = lane & 15, jg = lane >> 4;
    const int n = blockIdx.x * 4 + w;

    const float sc30 = ws[WS_PAR3+0], sc31 = ws[WS_PAR3+1], sc32 = ws[WS_PAR3+2], sc33 = ws[WS_PAR3+3];
    const float sh30 = ws[WS_PAR3+4], sh31 = ws[WS_PAR3+5], sh32 = ws[WS_PAR3+6], sh33 = ws[WS_PAR3+7];
    const float sc10 = ws[WS_PAR1+0], sc11 = ws[WS_PAR1+1], sh10 = ws[WS_PAR1+2], sh11 = ws[WS_PAR1+3];
    const float wp10 = Wp1[0], wp11 = Wp1[1], wp12 = Wp1[2], wp13 = Wp1[3];

    // phase A: logits w3[j][c0] for this wave's n
    const float4* w24 = reinterpret_cast<const float4*>(ws + WS_W2);
    float w3r[4];
    #pragma unroll
    for (int jj = 0; jj < 4; ++jj) {
        const int j = jg * 4 + jj, row = n * 16 + j;
        const float4 q = w24[row];
        const float h0 = fmaxf(fmaf(q.x, sc30, sh30), 0.f);
        const float h1 = fmaxf(fmaf(q.y, sc31, sh31), 0.f);
        const float h2 = fmaxf(fmaf(q.z, sc32, sh32), 0.f);
        const float h3 = fmaxf(fmaf(q.w, sc33, sh33), 0.f);
        const float acc = b2cs[c0] + W2cs[c0*4]*h0 + W2cs[c0*4+1]*h1
                        + W2cs[c0*4+2]*h2 + W2cs[c0*4+3]*h3;
        w3r[jj] = acc;
        smw[w][j][c0] = acc;
    }
    __syncthreads();
    // softmax over the 16 neighbors for column c0
    float mx = -1e30f;
    #pragma unroll
    for (int j = 0; j < K; ++j) mx = fmaxf(mx, smw[w][j][c0]);
    float ssum = 0.f;
    #pragma unroll
    for (int j = 0; j < K; ++j) ssum += __expf(smw[w][j][c0] - mx);
    const float rinv = 1.f / ssum;
    float wsm[4];
    #pragma unroll
    for (int jj = 0; jj < 4; ++jj) wsm[jj] = __expf(w3r[jj] - mx) * rinv;

    // phase B: gather features into LDS
    #pragma unroll
    for (int rep = 0; rep < 4; ++rep) {
        const int lin = rep * 64 + lane;
        const int j = lin >> 4, m = lin & 15;
        const int idxr = nbr_idx(n, j);
        fbuf[w][j * 17 + m] = reinterpret_cast<const float4*>(feat)[(size_t)idxr * 16 + m];
    }
    __syncthreads();

    // phase C: v = W3 @ f, register-blocked 4 rows x 8 col-groups
    float acc[32];
    #pragma unroll
    for (int x = 0; x < 32; ++x) acc[x] = 0.f;
    for (int m = 0; m < 16; ++m) {
        float4 wr[8];
        #pragma unroll
        for (int s = 0; s < 8; ++s) wr[s] = W3s[(c0 + 16 * s) * 17 + m];
        #pragma unroll
        for (int jj = 0; jj < 4; ++jj) {
            const float4 f = fbuf[w][(jg * 4 + jj) * 17 + m];
            #pragma unroll
            for (int s = 0; s < 8; ++s) acc[jj * 8 + s] += dot4(wr[s], f);
        }
    }

    // epilogue: + b3 + p_embed, * softmax weight, store
    #pragma unroll
    for (int jj = 0; jj < 4; ++jj) {
        const int j = jg * 4 + jj;
        const int row = n * 16 + j;
        const float2 tr = reinterpret_cast<const float2*>(out_trans)[row];
        const float p10 = wp10 * tr.x + wp11 * tr.y;
        const float p11 = wp12 * tr.x + wp13 * tr.y;
        const float ph0 = fmaxf(fmaf(p10, sc10, sh10), 0.f);
        const float ph1 = fmaxf(fmaf(p11, sc11, sh11), 0.f);
        #pragma unroll
        for (int s = 0; s < 8; ++s) {
            const int cc = c0 + 16 * s;
            const float4 wv = Wp2s[cc >> 1];
            const float w0 = (c0 & 1) ? wv.z : wv.x;
            const float w1 = (c0 & 1) ? wv.w : wv.y;
            const float pe = ph0 * w0 + ph1 * w1 + bp2s[cc];
            out[(size_t)row * COUT + cc] = (acc[jj * 8 + s] + b3s[cc] + pe) * wsm[jj];
        }
    }
}

extern "C" void kernel_launch(void* const* d_in, const int* in_sizes, int n_in,
                              void* d_out, int out_size, void* d_ws, size_t ws_size,
                              hipStream_t stream)
{
    const float* pts  = (const float*)d_in[0];
    const float* feat = (const float*)d_in[1];
    const float* W1   = (const float*)d_in[2];
    const float* b1   = (const float*)d_in[3];
    const float* Wb   = (const float*)d_in[4];
    const float* bb   = (const float*)d_in[5];
    const float* Wp1  = (const float*)d_in[6];
    const float* gp   = (const float*)d_in[7];
    const float* bp   = (const float*)d_in[8];
    const float* Wp2  = (const float*)d_in[9];
    const float* bp2  = (const float*)d_in[10];
    const float* W2a  = (const float*)d_in[11];
    const float* g2a  = (const float*)d_in[12];
    const float* b2a  = (const float*)d_in[13];
    const float* W2b  = (const float*)d_in[14];
    const float* g2b  = (const float*)d_in[15];
    const float* b2b  = (const float*)d_in[16];
    const float* W2c  = (const float*)d_in[17];
    const float* b2c  = (const float*)d_in[18];
    const float* W3   = (const float*)d_in[19];
    const float* b3   = (const float*)d_in[20];

    float* out       = (float*)d_out;
    float* out_trans = out + (size_t)NK * COUT;
    float* out_idx   = out_trans + (size_t)NK * 2;
    float* ws        = (float*)d_ws;

    hipMemsetAsync(ws, 0, 256 * sizeof(float), stream);  // zero BN sum accumulators
    k_stage1<<<NK / 256, 256, 0, stream>>>(pts, feat, W1, b1, Wb, bb, Wp1,
                                           out_trans, out_idx, ws);
    k_finalize<<<1, 2, 0, stream>>>(gp, bp, ws, WS_SUM1, WS_PAR1, 2);
    k_stage23<2><<<512, 256, 0, stream>>>(Wp1, Wp2, bp2, W2a, W2b, out_trans, ws);
    k_finalize<<<1, 32, 0, stream>>>(g2a, b2a, ws, WS_SUM2, WS_PAR2, 32);
    k_stage23<3><<<512, 256, 0, stream>>>(Wp1, Wp2, bp2, W2a, W2b, out_trans, ws);
    k_finalize<<<1, 4, 0, stream>>>(g2b, b2b, ws, WS_SUM3, WS_PAR3, 4);
    k_stage4<<<NPTS / 4, 256, 0, stream>>>(feat, Wp1, Wp2, bp2, W2c, b2c, W3, b3,
                                           out_trans, ws, out);
}

// Round 2
// 442.637 us; speedup vs baseline: 5.0655x; 5.0655x over previous
//
#include <hip/hip_runtime.h>

#define DEV static __device__ __forceinline__

namespace {
constexpr int PB   = 4096;      // points per batch
constexpr int NPTS = 32768;     // B*P
constexpr int RR   = 8;
constexpr int K    = 16;        // 2*r
constexpr int COUT = 128;
constexpr int MID  = 32;
constexpr int NK   = NPTS * K;  // 524288 rows
constexpr float BN_EPS = 1e-5f;

// ws float offsets
constexpr int WS_SUM1 = 0;      // 4:  s0,s1,q0,q1
constexpr int WS_SUM2 = 4;      // 64: s[32], q[32]
constexpr int WS_SUM3 = 68;     // 8:  s[4], q[4]
constexpr int WS_PAR1 = 80;     // 4:  sc[2], sh[2]
constexpr int WS_PAR2 = 84;     // 64: sc[32], sh[32]
constexpr int WS_PAR3 = 148;    // 8:  sc[4], sh[4]
constexpr size_t WS_ENERGY = 256;                         // NK*16 floats
constexpr size_t WS_W2     = WS_ENERGY + (size_t)NK * 16; // NK*4 floats
}

DEV int nbr_idx(int n, int j) {
    int b = n >> 12, i = n & (PB - 1);
    int o = (j < RR) ? (j - RR) : (j - RR + 1);
    return (b << 12) | ((i + o + PB) & (PB - 1));
}
DEV float dot4(float4 a, float4 b) { return a.x*b.x + a.y*b.y + a.z*b.z + a.w*b.w; }
DEV float wave_sum(float v) {
    #pragma unroll
    for (int off = 32; off >= 1; off >>= 1) v += __shfl_xor(v, off);
    return v;
}

// ---------------- stage 1: trans/idx, BN1 sums, e, energy ----------------
__global__ __launch_bounds__(256) void k_stage1(
    const float* __restrict__ pts, const float* __restrict__ feat,
    const float* __restrict__ W1, const float* __restrict__ b1,
    const float* __restrict__ Wb, const float* __restrict__ bb,
    const float* __restrict__ Wp1,
    float* __restrict__ out_trans, float* __restrict__ out_idx,
    float* __restrict__ ws)
{
    __shared__ float  W1t[K * 2];
    __shared__ float4 W1f[K * 16];
    __shared__ float  b1s[K], bbs[K];
    __shared__ float4 Wbs[K * K * 4];
    __shared__ float  red[4][4];

    const int t = threadIdx.x;
    const float4* Wb4 = reinterpret_cast<const float4*>(Wb);
    for (int x = t; x < K * K * 4; x += 256) Wbs[x] = Wb4[x];
    for (int x = t; x < K * 16; x += 256) {
        int o = x >> 4, m = x & 15;
        const float* w = W1 + o * 66 + 2 + m * 4;
        W1f[x] = make_float4(w[0], w[1], w[2], w[3]);
    }
    if (t < K * 2) W1t[t] = W1[(t >> 1) * 66 + (t & 1)];
    if (t < K) { b1s[t] = b1[t]; bbs[t] = bb[t]; }
    __syncthreads();

    const int row = blockIdx.x * 256 + t;
    const int n = row >> 4, j = row & 15;
    const int idxr = nbr_idx(n, j);
    const float tx = pts[2 * idxr]     - pts[2 * n];
    const float ty = pts[2 * idxr + 1] - pts[2 * n + 1];
    reinterpret_cast<float2*>(out_trans)[row] = make_float2(tx, ty);
    out_idx[row] = (float)idxr;

    // BN1 partial sums on p1 = trans @ Wp1^T
    {
        const float p10 = Wp1[0] * tx + Wp1[1] * ty;
        const float p11 = Wp1[2] * tx + Wp1[3] * ty;
        float v[4] = {p10, p11, p10 * p10, p11 * p11};
        #pragma unroll
        for (int q = 0; q < 4; ++q) {
            float s = wave_sum(v[q]);
            if ((t & 63) == 0) red[t >> 6][q] = s;
        }
        __syncthreads();
        if (t < 4) atomicAdd(&ws[WS_SUM1 + t], red[0][t] + red[1][t] + red[2][t] + red[3][t]);
    }

    float4 f4[16];
    const float4* fr = reinterpret_cast<const float4*>(feat) + (size_t)idxr * 16;
    #pragma unroll
    for (int m = 0; m < 16; ++m) f4[m] = fr[m];

    float e[K];
    #pragma unroll
    for (int o = 0; o < K; ++o) {
        float acc = b1s[o] + W1t[2 * o] * tx + W1t[2 * o + 1] * ty;
        #pragma unroll
        for (int m = 0; m < 16; ++m) acc += dot4(W1f[o * 16 + m], f4[m]);
        e[o] = fmaxf(acc, 0.f);
    }
    float4 e4[4];
    #pragma unroll
    for (int q = 0; q < 4; ++q) e4[q] = make_float4(e[4*q], e[4*q+1], e[4*q+2], e[4*q+3]);

    float* erow = ws + WS_ENERGY + (size_t)row * 16;
    for (int o = 0; o < K; ++o) {          // dynamic loop: keeps code size sane
        float acc = bbs[o];
        #pragma unroll
        for (int i = 0; i < K; ++i) {
            float u = 0.f;
            #pragma unroll
            for (int q = 0; q < 4; ++q) u += dot4(Wbs[(o * 16 + i) * 4 + q], e4[q]);
            acc = fmaf(e[i], u, acc);
        }
        erow[o] = acc;
    }
}

// ---------------- BN finalize: sums -> scale/shift ----------------
__global__ void k_finalize(const float* __restrict__ g, const float* __restrict__ b,
                           float* __restrict__ ws, int sum_off, int par_off, int nch)
{
    int c = threadIdx.x;
    if (c >= nch) return;
    const float invM = 1.f / (float)NK;
    float m = ws[sum_off + c] * invM;
    float q = ws[sum_off + nch + c] * invM;
    float rs = rsqrtf(q - m * m + BN_EPS);
    float sc = g[c] * rs;
    ws[par_off + c] = sc;
    ws[par_off + nch + c] = fmaf(-m, sc, b[c]);
}

// ---------------- stages 2 & 3: LDS-staged, channel-per-thread ----------------
// tile = 128 rows. x = [energy(16); shrink(16)] staged in LDS (row stride 36 floats).
// phase2: thread (q=t&31, g=t>>5) computes w1[q] for 16 rows, W2a row in registers.
// STAGE2: accumulate BN2 sums (2 regs/thread).
// STAGE3: write h=relu(bn2(w1)) back to LDS; phase3 thread (r=t>>2, p=t&3) computes
//         w2[r][p] (contiguous store) + BN3 sums (2 regs/thread).
template <int STAGE>
__global__ __launch_bounds__(256) void k_stage23(
    const float* __restrict__ Wp1, const float* __restrict__ Wp2,
    const float* __restrict__ bp2, const float* __restrict__ W2a,
    const float* __restrict__ W2b,
    const float* __restrict__ out_trans, float* __restrict__ ws)
{
    __shared__ float4 xs[128][9];          // 32 floats + 4 pad per row
    __shared__ float  sA0[16], sA1[16], sA2[16];
    __shared__ float  red[4][64];

    const int t = threadIdx.x;
    const int lane = t & 63, w = t >> 6;

    if (t < 16) {                          // shrink closed-form coefficients
        float a0 = 0.f, a1 = 0.f, a2 = 0.f;
        for (int a8 = 0; a8 < 8; ++a8) {
            const int c = a8 * 16 + t;
            a0 += Wp2[2 * c]; a1 += Wp2[2 * c + 1]; a2 += bp2[c];
        }
        sA0[t] = a0; sA1[t] = a1; sA2[t] = a2;
    }

    const int q = t & 31, g = t >> 5;      // phase-2 mapping
    float4 w2a4[8];
    const float4* W2a4 = reinterpret_cast<const float4*>(W2a);
    #pragma unroll
    for (int c = 0; c < 8; ++c) w2a4[c] = W2a4[q * 8 + c];

    const int p3 = t & 3;                  // phase-3 mapping
    float4 w2b4[8];
    float sc2 = 0.f, sh2 = 0.f;
    if (STAGE == 3) {
        const float4* W2b4 = reinterpret_cast<const float4*>(W2b);
        #pragma unroll
        for (int c = 0; c < 8; ++c) w2b4[c] = W2b4[p3 * 8 + c];
        sc2 = ws[WS_PAR2 + q];
        sh2 = ws[WS_PAR2 + 32 + q];
    }

    const float sc10 = ws[WS_PAR1 + 0], sc11 = ws[WS_PAR1 + 1];
    const float sh10 = ws[WS_PAR1 + 2], sh11 = ws[WS_PAR1 + 3];
    const float wp10 = Wp1[0], wp11 = Wp1[1], wp12 = Wp1[2], wp13 = Wp1[3];

    float s1 = 0.f, s2 = 0.f;

    const float4* en4p = reinterpret_cast<const float4*>(ws + WS_ENERGY);
    float* w2out = ws + WS_W2;
    float* xsf = reinterpret_cast<float*>(xs);

    for (int row0 = blockIdx.x * 128; row0 < NK; row0 += gridDim.x * 128) {
        __syncthreads();                   // protect xs vs previous tile readers
        // phase 1a: stream energy tile into LDS (fully coalesced)
        #pragma unroll
        for (int x = 0; x < 2; ++x) {
            const int lin = x * 256 + t;   // 0..511 = (row<<2)|c4
            xs[lin >> 2][lin & 3] = en4p[(size_t)row0 * 4 + lin];
        }
        // phase 1b: shrink (closed form) for 128 rows
        if (t < 128) {
            const float2 tr = reinterpret_cast<const float2*>(out_trans)[row0 + t];
            const float p10 = wp10 * tr.x + wp11 * tr.y;
            const float p11 = wp12 * tr.x + wp13 * tr.y;
            const float ph0 = fmaxf(fmaf(p10, sc10, sh10), 0.f);
            const float ph1 = fmaxf(fmaf(p11, sc11, sh11), 0.f);
            #pragma unroll
            for (int jq = 0; jq < 4; ++jq) {
                float4 v;
                v.x = fmaf(ph0, sA0[jq*4+0], fmaf(ph1, sA1[jq*4+0], sA2[jq*4+0]));
                v.y = fmaf(ph0, sA0[jq*4+1], fmaf(ph1, sA1[jq*4+1], sA2[jq*4+1]));
                v.z = fmaf(ph0, sA0[jq*4+2], fmaf(ph1, sA1[jq*4+2], sA2[jq*4+2]));
                v.w = fmaf(ph0, sA0[jq*4+3], fmaf(ph1, sA1[jq*4+3], sA2[jq*4+3]));
                xs[t][4 + jq] = v;
            }
        }
        __syncthreads();

        // phase 2: w1[q] for 16 rows
        float v[16];
        #pragma unroll
        for (int rr = 0; rr < 16; ++rr) {
            const int r = g * 16 + rr;
            float acc = 0.f;
            #pragma unroll
            for (int c = 0; c < 8; ++c) acc += dot4(w2a4[c], xs[r][c]);
            v[rr] = acc;
        }

        if (STAGE == 2) {
            #pragma unroll
            for (int rr = 0; rr < 16; ++rr) { s1 += v[rr]; s2 += v[rr] * v[rr]; }
        } else {
            __syncthreads();               // all reads of xs done
            #pragma unroll
            for (int rr = 0; rr < 16; ++rr) {
                const int r = g * 16 + rr;
                xsf[r * 36 + q] = fmaxf(fmaf(v[rr], sc2, sh2), 0.f);
            }
            __syncthreads();
            // phase 3: w2 = W2b @ h, contiguous store, BN3 sums
            #pragma unroll
            for (int half = 0; half < 2; ++half) {
                const int r = half * 64 + (t >> 2);
                float acc = 0.f;
                #pragma unroll
                for (int c = 0; c < 8; ++c) acc += dot4(w2b4[c], xs[r][c]);
                w2out[(size_t)(row0 + r) * 4 + p3] = acc;
                s1 += acc; s2 += acc * acc;
            }
        }
    }

    // block-level reduction of BN sums, one atomic set per block
    if (STAGE == 2) {
        s1 += __shfl_xor(s1, 32); s2 += __shfl_xor(s2, 32);   // fold the two g's
        if (lane < 32) { red[w][q] = s1; red[w][32 + q] = s2; }
        __syncthreads();
        if (t < 64) atomicAdd(&ws[WS_SUM2 + t],
                              red[0][t] + red[1][t] + red[2][t] + red[3][t]);
    } else {
        #pragma unroll
        for (int off = 4; off <= 32; off <<= 1) {
            s1 += __shfl_xor(s1, off); s2 += __shfl_xor(s2, off);
        }
        if (lane < 4) { red[w][lane] = s1; red[w][4 + lane] = s2; }
        __syncthreads();
        if (t < 8) atomicAdd(&ws[WS_SUM3 + t],
                             red[0][t] + red[1][t] + red[2][t] + red[3][t]);
    }
}

// ---------------- stage 4: softmax weights + v-matmul + combine ----------------
__global__ __launch_bounds__(256) void k_stage4(
    const float* __restrict__ feat, const float* __restrict__ Wp1,
    const float* __restrict__ Wp2, const float* __restrict__ bp2,
    const float* __restrict__ W2c, const float* __restrict__ b2c,
    const float* __restrict__ W3, const float* __restrict__ b3,
    const float* __restrict__ out_trans, const float* __restrict__ ws,
    float* __restrict__ out)
{
    __shared__ float4 W3s[COUT * 17];    // [cout][16 float4 + 1 pad]
    __shared__ float4 fbuf[4][K * 17];   // per-wave gathered features
    __shared__ float  smw[4][K][17];     // softmax logits
    __shared__ float4 Wp2s[64];
    __shared__ float  bp2s[COUT], b3s[COUT], W2cs[64], b2cs[K];

    const int t = threadIdx.x;
    const float4* W34 = reinterpret_cast<const float4*>(W3);
    for (int x = t; x < COUT * 16; x += 256) W3s[(x >> 4) * 17 + (x & 15)] = W34[x];
    for (int x = t; x < 64; x += 256) Wp2s[x] = reinterpret_cast<const float4*>(Wp2)[x];
    for (int x = t; x < COUT; x += 256) { bp2s[x] = bp2[x]; b3s[x] = b3[x]; }
    for (int x = t; x < 64; x += 256) W2cs[x] = W2c[x];
    if (t < K) b2cs[t] = b2c[t];
    __syncthreads();

    const int w = t >> 6, lane = t & 63;
    const int c0 = lane & 15, jg = lane >> 4;
    const int n = blockIdx.x * 4 + w;

    const float sc30 = ws[WS_PAR3+0], sc31 = ws[WS_PAR3+1], sc32 = ws[WS_PAR3+2], sc33 = ws[WS_PAR3+3];
    const float sh30 = ws[WS_PAR3+4], sh31 = ws[WS_PAR3+5], sh32 = ws[WS_PAR3+6], sh33 = ws[WS_PAR3+7];
    const float sc10 = ws[WS_PAR1+0], sc11 = ws[WS_PAR1+1], sh10 = ws[WS_PAR1+2], sh11 = ws[WS_PAR1+3];
    const float wp10 = Wp1[0], wp11 = Wp1[1], wp12 = Wp1[2], wp13 = Wp1[3];

    // phase A: logits w3[j][c0] for this wave's n
    const float4* w24 = reinterpret_cast<const float4*>(ws + WS_W2);
    float w3r[4];
    #pragma unroll
    for (int jj = 0; jj < 4; ++jj) {
        const int j = jg * 4 + jj, row = n * 16 + j;
        const float4 q = w24[row];
        const float h0 = fmaxf(fmaf(q.x, sc30, sh30), 0.f);
        const float h1 = fmaxf(fmaf(q.y, sc31, sh31), 0.f);
        const float h2 = fmaxf(fmaf(q.z, sc32, sh32), 0.f);
        const float h3 = fmaxf(fmaf(q.w, sc33, sh33), 0.f);
        const float acc = b2cs[c0] + W2cs[c0*4]*h0 + W2cs[c0*4+1]*h1
                        + W2cs[c0*4+2]*h2 + W2cs[c0*4+3]*h3;
        w3r[jj] = acc;
        smw[w][j][c0] = acc;
    }
    __syncthreads();
    // softmax over the 16 neighbors for column c0
    float mx = -1e30f;
    #pragma unroll
    for (int j = 0; j < K; ++j) mx = fmaxf(mx, smw[w][j][c0]);
    float ssum = 0.f;
    #pragma unroll
    for (int j = 0; j < K; ++j) ssum += __expf(smw[w][j][c0] - mx);
    const float rinv = 1.f / ssum;
    float wsm[4];
    #pragma unroll
    for (int jj = 0; jj < 4; ++jj) wsm[jj] = __expf(w3r[jj] - mx) * rinv;

    // phase B: gather features into LDS
    #pragma unroll
    for (int rep = 0; rep < 4; ++rep) {
        const int lin = rep * 64 + lane;
        const int j = lin >> 4, m = lin & 15;
        const int idxr = nbr_idx(n, j);
        fbuf[w][j * 17 + m] = reinterpret_cast<const float4*>(feat)[(size_t)idxr * 16 + m];
    }
    __syncthreads();

    // phase C: v = W3 @ f, register-blocked 4 rows x 8 col-groups
    float acc[32];
    #pragma unroll
    for (int x = 0; x < 32; ++x) acc[x] = 0.f;
    for (int m = 0; m < 16; ++m) {
        float4 wr[8];
        #pragma unroll
        for (int s = 0; s < 8; ++s) wr[s] = W3s[(c0 + 16 * s) * 17 + m];
        #pragma unroll
        for (int jj = 0; jj < 4; ++jj) {
            const float4 f = fbuf[w][(jg * 4 + jj) * 17 + m];
            #pragma unroll
            for (int s = 0; s < 8; ++s) acc[jj * 8 + s] += dot4(wr[s], f);
        }
    }

    // epilogue: + b3 + p_embed, * softmax weight, store
    #pragma unroll
    for (int jj = 0; jj < 4; ++jj) {
        const int j = jg * 4 + jj;
        const int row = n * 16 + j;
        const float2 tr = reinterpret_cast<const float2*>(out_trans)[row];
        const float p10 = wp10 * tr.x + wp11 * tr.y;
        const float p11 = wp12 * tr.x + wp13 * tr.y;
        const float ph0 = fmaxf(fmaf(p10, sc10, sh10), 0.f);
        const float ph1 = fmaxf(fmaf(p11, sc11, sh11), 0.f);
        #pragma unroll
        for (int s = 0; s < 8; ++s) {
            const int cc = c0 + 16 * s;
            const float4 wv = Wp2s[cc >> 1];
            const float w0 = (c0 & 1) ? wv.z : wv.x;
            const float w1 = (c0 & 1) ? wv.w : wv.y;
            const float pe = ph0 * w0 + ph1 * w1 + bp2s[cc];
            out[(size_t)row * COUT + cc] = (acc[jj * 8 + s] + b3s[cc] + pe) * wsm[jj];
        }
    }
}

extern "C" void kernel_launch(void* const* d_in, const int* in_sizes, int n_in,
                              void* d_out, int out_size, void* d_ws, size_t ws_size,
                              hipStream_t stream)
{
    const float* pts  = (const float*)d_in[0];
    const float* feat = (const float*)d_in[1];
    const float* W1   = (const float*)d_in[2];
    const float* b1   = (const float*)d_in[3];
    const float* Wb   = (const float*)d_in[4];
    const float* bb   = (const float*)d_in[5];
    const float* Wp1  = (const float*)d_in[6];
    const float* gp   = (const float*)d_in[7];
    const float* bp   = (const float*)d_in[8];
    const float* Wp2  = (const float*)d_in[9];
    const float* bp2  = (const float*)d_in[10];
    const float* W2a  = (const float*)d_in[11];
    const float* g2a  = (const float*)d_in[12];
    const float* b2a  = (const float*)d_in[13];
    const float* W2b  = (const float*)d_in[14];
    const float* g2b  = (const float*)d_in[15];
    const float* b2b  = (const float*)d_in[16];
    const float* W2c  = (const float*)d_in[17];
    const float* b2c  = (const float*)d_in[18];
    const float* W3   = (const float*)d_in[19];
    const float* b3   = (const float*)d_in[20];

    float* out       = (float*)d_out;
    float* out_trans = out + (size_t)NK * COUT;
    float* out_idx   = out_trans + (size_t)NK * 2;
    float* ws        = (float*)d_ws;

    hipMemsetAsync(ws, 0, 256 * sizeof(float), stream);  // zero BN sum accumulators
    k_stage1<<<NK / 256, 256, 0, stream>>>(pts, feat, W1, b1, Wb, bb, Wp1,
                                           out_trans, out_idx, ws);
    k_finalize<<<1, 2, 0, stream>>>(gp, bp, ws, WS_SUM1, WS_PAR1, 2);
    k_stage23<2><<<2048, 256, 0, stream>>>(Wp1, Wp2, bp2, W2a, W2b, out_trans, ws);
    k_finalize<<<1, 32, 0, stream>>>(g2a, b2a, ws, WS_SUM2, WS_PAR2, 32);
    k_stage23<3><<<2048, 256, 0, stream>>>(Wp1, Wp2, bp2, W2a, W2b, out_trans, ws);
    k_finalize<<<1, 4, 0, stream>>>(g2b, b2b, ws, WS_SUM3, WS_PAR3, 4);
    k_stage4<<<NPTS / 4, 256, 0, stream>>>(feat, Wp1, Wp2, bp2, W2c, b2c, W3, b3,
                                           out_trans, ws, out);
}

// Round 3
// 411.325 us; speedup vs baseline: 5.4511x; 1.0761x over previous
//
#include <hip/hip_runtime.h>

#define DEV static __device__ __forceinline__

namespace {
constexpr int PB   = 4096;      // points per batch
constexpr int NPTS = 32768;     // B*P
constexpr int RR   = 8;
constexpr int K    = 16;        // 2*r
constexpr int COUT = 128;
constexpr int MID  = 32;
constexpr int NK   = NPTS * K;  // 524288 rows
constexpr float BN_EPS = 1e-5f;

// ws float offsets
constexpr int WS_SUM1 = 0;      // 4:  s0,s1,q0,q1
constexpr int WS_SUM2 = 4;      // 64: s[32], q[32]
constexpr int WS_SUM3 = 68;     // 8:  s[4], q[4]
constexpr int WS_PAR1 = 80;     // 4:  sc[2], sh[2]
constexpr int WS_PAR2 = 84;     // 64: sc[32], sh[32]
constexpr int WS_PAR3 = 148;    // 8:  sc[4], sh[4]
constexpr size_t WS_ENERGY = 256;                         // NK*16 floats
constexpr size_t WS_W2     = WS_ENERGY + (size_t)NK * 16; // NK*4 floats
}

typedef __attribute__((ext_vector_type(8))) __bf16 bf16x8;
typedef __attribute__((ext_vector_type(4))) float  f32x4;

DEV int nbr_idx(int n, int j) {
    int b = n >> 12, i = n & (PB - 1);
    int o = (j < RR) ? (j - RR) : (j - RR + 1);
    return (b << 12) | ((i + o + PB) & (PB - 1));
}
DEV float dot4(float4 a, float4 b) { return a.x*b.x + a.y*b.y + a.z*b.z + a.w*b.w; }
DEV float wave_sum(float v) {
    #pragma unroll
    for (int off = 32; off >= 1; off >>= 1) v += __shfl_xor(v, off);
    return v;
}
DEV bf16x8 cvt8(float4 a, float4 b) {
    bf16x8 r;
    r[0] = (__bf16)a.x; r[1] = (__bf16)a.y; r[2] = (__bf16)a.z; r[3] = (__bf16)a.w;
    r[4] = (__bf16)b.x; r[5] = (__bf16)b.y; r[6] = (__bf16)b.z; r[7] = (__bf16)b.w;
    return r;
}

// ---------------- stage 1 (MFMA): trans/idx, BN1 sums, e, energy ----------------
// One wave per n (16 neighbor rows). e-tile = 2 MFMAs (K=64 feat; trans part in
// C-init). energy = E2 @ Wb^T as 8 MFMAs (K=256), E2 formed in-register from the
// LDS-transposed e-tile. MFMA lane mapping (16x16x32 bf16, verified m89):
//   A: row=l&15, k=(l>>4)*8+e ; B: col=l&15, same k ; C/D: row=(l>>4)*4+reg, col=l&15.
__global__ __launch_bounds__(256) void k_stage1(
    const float* __restrict__ pts, const float* __restrict__ feat,
    const float* __restrict__ W1, const float* __restrict__ b1,
    const float* __restrict__ Wb, const float* __restrict__ bb,
    const float* __restrict__ Wp1,
    float* __restrict__ out_trans, float* __restrict__ out_idx,
    float* __restrict__ ws)
{
    __shared__ float ts[4][16][2];     // per-wave trans tile
    __shared__ float es[4][16][20];    // per-wave e tile (stride 20: aligned + spread)
    __shared__ float red[4][4];
    __shared__ float W1ts[32], b1s[16], bbs[16];

    const int t = threadIdx.x, w = t >> 6, l = t & 63, c0 = l & 15, jg = l >> 4;
    const int n = blockIdx.x * 4 + w;

    if (t < 32) W1ts[t] = W1[(t >> 1) * 66 + (t & 1)];
    if (t < 16) { b1s[t] = b1[t]; bbs[t] = bb[t]; }

    // B-frags: W1 (feat part), rows o=c0, k=kf*32+jg*8+e  (row stride 66 -> float2 loads)
    bf16x8 w1b[2];
    #pragma unroll
    for (int kf = 0; kf < 2; ++kf) {
        const float* p = W1 + c0 * 66 + 2 + kf * 32 + jg * 8;
        const float2 q0 = *(const float2*)(p),     q1 = *(const float2*)(p + 2);
        const float2 q2 = *(const float2*)(p + 4), q3 = *(const float2*)(p + 6);
        w1b[kf] = cvt8(make_float4(q0.x, q0.y, q1.x, q1.y),
                       make_float4(q2.x, q2.y, q3.x, q3.y));
    }
    // B-frags: Wb flat [o][256], o=c0, k=g*32+jg*8+e
    bf16x8 wbb[8];
    #pragma unroll
    for (int g = 0; g < 8; ++g) {
        const float4* p = (const float4*)(Wb + c0 * 256 + g * 32 + jg * 8);
        wbb[g] = cvt8(p[0], p[1]);
    }

    // phase a: all lanes compute row j=c0 (4x duplicated across jg)
    const int idxr = nbr_idx(n, c0);
    const float2 pn = ((const float2*)pts)[n];
    const float2 pq = ((const float2*)pts)[idxr];
    const float tx = pq.x - pn.x, ty = pq.y - pn.y;
    if (jg == 0) {
        ts[w][c0][0] = tx; ts[w][c0][1] = ty;
        ((float2*)out_trans)[n * 16 + c0] = make_float2(tx, ty);
        out_idx[n * 16 + c0] = (float)idxr;
    }
    {
        const float p10 = Wp1[0] * tx + Wp1[1] * ty;
        const float p11 = Wp1[2] * tx + Wp1[3] * ty;
        float v[4] = {p10, p11, p10 * p10, p11 * p11};
        #pragma unroll
        for (int q = 0; q < 4; ++q) {
            float s = wave_sum(v[q]);          // 4x over-counted (jg dup)
            if (l == 0) red[w][q] = s;
        }
    }

    // A-frags: gathered features for row j=c0
    const float4* fb = (const float4*)(feat + (size_t)idxr * 64 + jg * 8);
    const bf16x8 fa0 = cvt8(fb[0], fb[1]);
    const bf16x8 fa1 = cvt8(fb[8], fb[9]);

    __syncthreads();
    if (t < 4) atomicAdd(&ws[WS_SUM1 + t],
                         0.25f * (red[0][t] + red[1][t] + red[2][t] + red[3][t]));

    // e-tile: C-init with bias + trans part, then 2 MFMAs over feat
    f32x4 acc;
    #pragma unroll
    for (int r = 0; r < 4; ++r) {
        const int row = jg * 4 + r;
        acc[r] = b1s[c0] + W1ts[2 * c0] * ts[w][row][0] + W1ts[2 * c0 + 1] * ts[w][row][1];
    }
    acc = __builtin_amdgcn_mfma_f32_16x16x32_bf16(fa0, w1b[0], acc, 0, 0, 0);
    acc = __builtin_amdgcn_mfma_f32_16x16x32_bf16(fa1, w1b[1], acc, 0, 0, 0);
    #pragma unroll
    for (int r = 0; r < 4; ++r) es[w][jg * 4 + r][c0] = fmaxf(acc[r], 0.f);

    __syncthreads();

    // read back e row c0 (the A-row this lane feeds)
    const float4 ef0 = *(const float4*)&es[w][c0][0];
    const float4 ef1 = *(const float4*)&es[w][c0][4];
    const float4 ef2 = *(const float4*)&es[w][c0][8];
    const float4 ef3 = *(const float4*)&es[w][c0][12];
    const float ev[16] = {ef0.x, ef0.y, ef0.z, ef0.w, ef1.x, ef1.y, ef1.z, ef1.w,
                          ef2.x, ef2.y, ef2.z, ef2.w, ef3.x, ef3.y, ef3.z, ef3.w};
    const bool hi = (jg & 1);       // j0 = 8*(jg&1)
    const bool ih = (jg >> 1);      // i  = 2g + (jg>>1)
    float eh[8];
    #pragma unroll
    for (int e = 0; e < 8; ++e) eh[e] = hi ? ev[8 + e] : ev[e];

    f32x4 acc2;
    #pragma unroll
    for (int r = 0; r < 4; ++r) acc2[r] = bbs[c0];
    #pragma unroll
    for (int g = 0; g < 8; ++g) {
        const float ei = ih ? ev[2 * g + 1] : ev[2 * g];
        bf16x8 a2;
        #pragma unroll
        for (int e = 0; e < 8; ++e) a2[e] = (__bf16)(ei * eh[e]);
        acc2 = __builtin_amdgcn_mfma_f32_16x16x32_bf16(a2, wbb[g], acc2, 0, 0, 0);
    }
    float* ebase = ws + WS_ENERGY + (size_t)n * 256;
    #pragma unroll
    for (int r = 0; r < 4; ++r) ebase[(jg * 4 + r) * 16 + c0] = acc2[r];
}

// ---------------- BN finalize: sums -> scale/shift ----------------
__global__ void k_finalize(const float* __restrict__ g, const float* __restrict__ b,
                           float* __restrict__ ws, int sum_off, int par_off, int nch)
{
    int c = threadIdx.x;
    if (c >= nch) return;
    const float invM = 1.f / (float)NK;
    float m = ws[sum_off + c] * invM;
    float q = ws[sum_off + nch + c] * invM;
    float rs = rsqrtf(q - m * m + BN_EPS);
    float sc = g[c] * rs;
    ws[par_off + c] = sc;
    ws[par_off + nch + c] = fmaf(-m, sc, b[c]);
}

// ---------------- stages 2 & 3: LDS-staged, channel-per-thread ----------------
template <int STAGE>
__global__ __launch_bounds__(256) void k_stage23(
    const float* __restrict__ Wp1, const float* __restrict__ Wp2,
    const float* __restrict__ bp2, const float* __restrict__ W2a,
    const float* __restrict__ W2b,
    const float* __restrict__ out_trans, float* __restrict__ ws)
{
    __shared__ float4 xs[128][9];          // 32 floats + 4 pad per row
    __shared__ float  sA0[16], sA1[16], sA2[16];
    __shared__ float  red[4][64];

    const int t = threadIdx.x;
    const int lane = t & 63, w = t >> 6;

    if (t < 16) {                          // shrink closed-form coefficients
        float a0 = 0.f, a1 = 0.f, a2 = 0.f;
        for (int a8 = 0; a8 < 8; ++a8) {
            const int c = a8 * 16 + t;
            a0 += Wp2[2 * c]; a1 += Wp2[2 * c + 1]; a2 += bp2[c];
        }
        sA0[t] = a0; sA1[t] = a1; sA2[t] = a2;
    }

    const int q = t & 31, g = t >> 5;      // phase-2 mapping
    float4 w2a4[8];
    const float4* W2a4 = reinterpret_cast<const float4*>(W2a);
    #pragma unroll
    for (int c = 0; c < 8; ++c) w2a4[c] = W2a4[q * 8 + c];

    const int p3 = t & 3;                  // phase-3 mapping
    float4 w2b4[8];
    float sc2 = 0.f, sh2 = 0.f;
    if (STAGE == 3) {
        const float4* W2b4 = reinterpret_cast<const float4*>(W2b);
        #pragma unroll
        for (int c = 0; c < 8; ++c) w2b4[c] = W2b4[p3 * 8 + c];
        sc2 = ws[WS_PAR2 + q];
        sh2 = ws[WS_PAR2 + 32 + q];
    }

    const float sc10 = ws[WS_PAR1 + 0], sc11 = ws[WS_PAR1 + 1];
    const float sh10 = ws[WS_PAR1 + 2], sh11 = ws[WS_PAR1 + 3];
    const float wp10 = Wp1[0], wp11 = Wp1[1], wp12 = Wp1[2], wp13 = Wp1[3];

    float s1 = 0.f, s2 = 0.f;

    const float4* en4p = reinterpret_cast<const float4*>(ws + WS_ENERGY);
    float* w2out = ws + WS_W2;
    float* xsf = reinterpret_cast<float*>(xs);

    for (int row0 = blockIdx.x * 128; row0 < NK; row0 += gridDim.x * 128) {
        __syncthreads();                   // protect xs vs previous tile readers
        #pragma unroll
        for (int x = 0; x < 2; ++x) {
            const int lin = x * 256 + t;   // 0..511 = (row<<2)|c4
            xs[lin >> 2][lin & 3] = en4p[(size_t)row0 * 4 + lin];
        }
        if (t < 128) {
            const float2 tr = reinterpret_cast<const float2*>(out_trans)[row0 + t];
            const float p10 = wp10 * tr.x + wp11 * tr.y;
            const float p11 = wp12 * tr.x + wp13 * tr.y;
            const float ph0 = fmaxf(fmaf(p10, sc10, sh10), 0.f);
            const float ph1 = fmaxf(fmaf(p11, sc11, sh11), 0.f);
            #pragma unroll
            for (int jq = 0; jq < 4; ++jq) {
                float4 v;
                v.x = fmaf(ph0, sA0[jq*4+0], fmaf(ph1, sA1[jq*4+0], sA2[jq*4+0]));
                v.y = fmaf(ph0, sA0[jq*4+1], fmaf(ph1, sA1[jq*4+1], sA2[jq*4+1]));
                v.z = fmaf(ph0, sA0[jq*4+2], fmaf(ph1, sA1[jq*4+2], sA2[jq*4+2]));
                v.w = fmaf(ph0, sA0[jq*4+3], fmaf(ph1, sA1[jq*4+3], sA2[jq*4+3]));
                xs[t][4 + jq] = v;
            }
        }
        __syncthreads();

        float v[16];
        #pragma unroll
        for (int rr = 0; rr < 16; ++rr) {
            const int r = g * 16 + rr;
            float acc = 0.f;
            #pragma unroll
            for (int c = 0; c < 8; ++c) acc += dot4(w2a4[c], xs[r][c]);
            v[rr] = acc;
        }

        if (STAGE == 2) {
            #pragma unroll
            for (int rr = 0; rr < 16; ++rr) { s1 += v[rr]; s2 += v[rr] * v[rr]; }
        } else {
            __syncthreads();               // all reads of xs done
            #pragma unroll
            for (int rr = 0; rr < 16; ++rr) {
                const int r = g * 16 + rr;
                xsf[r * 36 + q] = fmaxf(fmaf(v[rr], sc2, sh2), 0.f);
            }
            __syncthreads();
            #pragma unroll
            for (int half = 0; half < 2; ++half) {
                const int r = half * 64 + (t >> 2);
                float acc = 0.f;
                #pragma unroll
                for (int c = 0; c < 8; ++c) acc += dot4(w2b4[c], xs[r][c]);
                w2out[(size_t)(row0 + r) * 4 + p3] = acc;
                s1 += acc; s2 += acc * acc;
            }
        }
    }

    if (STAGE == 2) {
        s1 += __shfl_xor(s1, 32); s2 += __shfl_xor(s2, 32);
        if (lane < 32) { red[w][q] = s1; red[w][32 + q] = s2; }
        __syncthreads();
        if (t < 64) atomicAdd(&ws[WS_SUM2 + t],
                              red[0][t] + red[1][t] + red[2][t] + red[3][t]);
    } else {
        #pragma unroll
        for (int off = 4; off <= 32; off <<= 1) {
            s1 += __shfl_xor(s1, off); s2 += __shfl_xor(s2, off);
        }
        if (lane < 4) { red[w][lane] = s1; red[w][4 + lane] = s2; }
        __syncthreads();
        if (t < 8) atomicAdd(&ws[WS_SUM3 + t],
                             red[0][t] + red[1][t] + red[2][t] + red[3][t]);
    }
}

// ---------------- stage 4 (MFMA): softmax weights + v-matmul + combine ----------------
// One wave per n. D tiles 16(j) x 16(cc), 8 tiles x K=64 -> 16 MFMAs.
// W3^T held as bf16 B-frags in registers; bias+p_embed folded into C-init;
// logits/softmax computed directly in the C/D lane mapping (no LDS transpose).
__global__ __launch_bounds__(256) void k_stage4(
    const float* __restrict__ feat, const float* __restrict__ Wp1,
    const float* __restrict__ Wp2, const float* __restrict__ bp2,
    const float* __restrict__ W2c, const float* __restrict__ b2c,
    const float* __restrict__ W3, const float* __restrict__ b3,
    const float* __restrict__ out_trans, const float* __restrict__ ws,
    float* __restrict__ out)
{
    __shared__ float wp2a[COUT], wp2b[COUT], pb3[COUT], w2cs[64], b2cs[16];

    const int t = threadIdx.x, w = t >> 6, l = t & 63, c0 = l & 15, jg = l >> 4;
    const int n = blockIdx.x * 4 + w;

    for (int x = t; x < COUT; x += 256) {
        wp2a[x] = Wp2[2 * x]; wp2b[x] = Wp2[2 * x + 1]; pb3[x] = bp2[x] + b3[x];
    }
    if (t < 64) w2cs[t] = W2c[t];
    if (t < 16) b2cs[t] = b2c[t];
    __syncthreads();

    // B-frags: W3^T, col = 16s+c0, k = kf*32 + jg*8 + e
    bf16x8 w3b[16];
    #pragma unroll
    for (int s = 0; s < 8; ++s) {
        const float* rowp = W3 + (size_t)(16 * s + c0) * 64 + jg * 8;
        const float4* p0 = (const float4*)rowp;
        const float4* p1 = (const float4*)(rowp + 32);
        w3b[2 * s]     = cvt8(p0[0], p0[1]);
        w3b[2 * s + 1] = cvt8(p1[0], p1[1]);
    }

    const float sc30 = ws[WS_PAR3+0], sc31 = ws[WS_PAR3+1], sc32 = ws[WS_PAR3+2], sc33 = ws[WS_PAR3+3];
    const float sh30 = ws[WS_PAR3+4], sh31 = ws[WS_PAR3+5], sh32 = ws[WS_PAR3+6], sh33 = ws[WS_PAR3+7];
    const float sc10 = ws[WS_PAR1+0], sc11 = ws[WS_PAR1+1], sh10 = ws[WS_PAR1+2], sh11 = ws[WS_PAR1+3];
    const float wp10 = Wp1[0], wp11 = Wp1[1], wp12 = Wp1[2], wp13 = Wp1[3];

    // logits for rows j = jg*4+jj, col c0 (exactly the C/D mapping)
    const float4* w24 = (const float4*)(ws + WS_W2);
    float lg[4];
    #pragma unroll
    for (int jj = 0; jj < 4; ++jj) {
        const float4 q = w24[n * 16 + jg * 4 + jj];
        const float h0 = fmaxf(fmaf(q.x, sc30, sh30), 0.f);
        const float h1 = fmaxf(fmaf(q.y, sc31, sh31), 0.f);
        const float h2 = fmaxf(fmaf(q.z, sc32, sh32), 0.f);
        const float h3 = fmaxf(fmaf(q.w, sc33, sh33), 0.f);
        lg[jj] = b2cs[c0] + w2cs[c0*4]*h0 + w2cs[c0*4+1]*h1
               + w2cs[c0*4+2]*h2 + w2cs[c0*4+3]*h3;
    }
    // softmax over 16 j's for this c0: in-lane 4 + exchange across jg bits
    float mx = fmaxf(fmaxf(lg[0], lg[1]), fmaxf(lg[2], lg[3]));
    mx = fmaxf(mx, __shfl_xor(mx, 16));
    mx = fmaxf(mx, __shfl_xor(mx, 32));
    float ex[4], ss = 0.f;
    #pragma unroll
    for (int jj = 0; jj < 4; ++jj) { ex[jj] = __expf(lg[jj] - mx); ss += ex[jj]; }
    ss += __shfl_xor(ss, 16);
    ss += __shfl_xor(ss, 32);
    const float rinv = 1.f / ss;

    // p-path scalars per row
    float ph0[4], ph1[4];
    #pragma unroll
    for (int jj = 0; jj < 4; ++jj) {
        const float2 tr = ((const float2*)out_trans)[n * 16 + jg * 4 + jj];
        const float p10 = wp10 * tr.x + wp11 * tr.y;
        const float p11 = wp12 * tr.x + wp13 * tr.y;
        ph0[jj] = fmaxf(fmaf(p10, sc10, sh10), 0.f);
        ph1[jj] = fmaxf(fmaf(p11, sc11, sh11), 0.f);
    }

    // C-init = b3 + bp2 + p_embed
    f32x4 accs[8];
    #pragma unroll
    for (int s = 0; s < 8; ++s) {
        const int cc = 16 * s + c0;
        const float a0 = wp2a[cc], a1 = wp2b[cc], cb = pb3[cc];
        #pragma unroll
        for (int jj = 0; jj < 4; ++jj)
            accs[s][jj] = fmaf(ph0[jj], a0, fmaf(ph1[jj], a1, cb));
    }

    // A-frags: gathered features for row j=c0
    const int idxr = nbr_idx(n, c0);
    const float4* fb = (const float4*)(feat + (size_t)idxr * 64 + jg * 8);
    const bf16x8 fa0 = cvt8(fb[0], fb[1]);
    const bf16x8 fa1 = cvt8(fb[8], fb[9]);

    #pragma unroll
    for (int s = 0; s < 8; ++s) {
        accs[s] = __builtin_amdgcn_mfma_f32_16x16x32_bf16(fa0, w3b[2*s],   accs[s], 0, 0, 0);
        accs[s] = __builtin_amdgcn_mfma_f32_16x16x32_bf16(fa1, w3b[2*s+1], accs[s], 0, 0, 0);
    }

    float* ob = out + (size_t)n * 16 * COUT;
    #pragma unroll
    for (int jj = 0; jj < 4; ++jj) {
        const float wgt = ex[jj] * rinv;
        #pragma unroll
        for (int s = 0; s < 8; ++s)
            ob[(jg * 4 + jj) * COUT + 16 * s + c0] = accs[s][jj] * wgt;
    }
}

extern "C" void kernel_launch(void* const* d_in, const int* in_sizes, int n_in,
                              void* d_out, int out_size, void* d_ws, size_t ws_size,
                              hipStream_t stream)
{
    const float* pts  = (const float*)d_in[0];
    const float* feat = (const float*)d_in[1];
    const float* W1   = (const float*)d_in[2];
    const float* b1   = (const float*)d_in[3];
    const float* Wb   = (const float*)d_in[4];
    const float* bb   = (const float*)d_in[5];
    const float* Wp1  = (const float*)d_in[6];
    const float* gp   = (const float*)d_in[7];
    const float* bp   = (const float*)d_in[8];
    const float* Wp2  = (const float*)d_in[9];
    const float* bp2  = (const float*)d_in[10];
    const float* W2a  = (const float*)d_in[11];
    const float* g2a  = (const float*)d_in[12];
    const float* b2a  = (const float*)d_in[13];
    const float* W2b  = (const float*)d_in[14];
    const float* g2b  = (const float*)d_in[15];
    const float* b2b  = (const float*)d_in[16];
    const float* W2c  = (const float*)d_in[17];
    const float* b2c  = (const float*)d_in[18];
    const float* W3   = (const float*)d_in[19];
    const float* b3   = (const float*)d_in[20];

    float* out       = (float*)d_out;
    float* out_trans = out + (size_t)NK * COUT;
    float* out_idx   = out_trans + (size_t)NK * 2;
    float* ws        = (float*)d_ws;

    hipMemsetAsync(ws, 0, 256 * sizeof(float), stream);  // zero BN sum accumulators
    k_stage1<<<NPTS / 4, 256, 0, stream>>>(pts, feat, W1, b1, Wb, bb, Wp1,
                                           out_trans, out_idx, ws);
    k_finalize<<<1, 2, 0, stream>>>(gp, bp, ws, WS_SUM1, WS_PAR1, 2);
    k_stage23<2><<<2048, 256, 0, stream>>>(Wp1, Wp2, bp2, W2a, W2b, out_trans, ws);
    k_finalize<<<1, 32, 0, stream>>>(g2a, b2a, ws, WS_SUM2, WS_PAR2, 32);
    k_stage23<3><<<2048, 256, 0, stream>>>(Wp1, Wp2, bp2, W2a, W2b, out_trans, ws);
    k_finalize<<<1, 4, 0, stream>>>(g2b, b2b, ws, WS_SUM3, WS_PAR3, 4);
    k_stage4<<<NPTS / 4, 256, 0, stream>>>(feat, Wp1, Wp2, bp2, W2c, b2c, W3, b3,
                                           out_trans, ws, out);
}

// Round 4
// 357.162 us; speedup vs baseline: 6.2777x; 1.1517x over previous
//
#include <hip/hip_runtime.h>

#define DEV static __device__ __forceinline__

namespace {
constexpr int PB   = 4096;
constexpr int NPTS = 32768;
constexpr int RR   = 8;
constexpr int K    = 16;
constexpr int COUT = 128;
constexpr int NK   = NPTS * K;    // 524288
constexpr float BN_EPS = 1e-5f;

// ws float offsets
constexpr int    WS_SUM1 = 0;                         // 4
constexpr int    WS_SUM2 = 4;                         // 64
constexpr int    WS_SUM3 = 68;                        // 8
constexpr size_t WS_P2   = 256;                       // 8192*64 f32 BN2 block partials
constexpr size_t WS_W1   = WS_P2 + 8192 * 64;         // NK*32 bf16 (= NK*16 f32-equiv)
constexpr size_t WS_W2   = WS_W1 + (size_t)NK * 16;   // NK*4 f32
}

typedef __attribute__((ext_vector_type(8))) __bf16 bf16x8;
typedef __attribute__((ext_vector_type(4))) float  f32x4;

DEV int nbr_idx(int n, int j) {
    int b = n >> 12, i = n & (PB - 1);
    int o = (j < RR) ? (j - RR) : (j - RR + 1);
    return (b << 12) | ((i + o + PB) & (PB - 1));
}
DEV float wave_sum(float v) {
    #pragma unroll
    for (int off = 32; off >= 1; off >>= 1) v += __shfl_xor(v, off);
    return v;
}
DEV bf16x8 cvt8(float4 a, float4 b) {
    bf16x8 r;
    r[0] = (__bf16)a.x; r[1] = (__bf16)a.y; r[2] = (__bf16)a.z; r[3] = (__bf16)a.w;
    r[4] = (__bf16)b.x; r[5] = (__bf16)b.y; r[6] = (__bf16)b.z; r[7] = (__bf16)b.w;
    return r;
}
DEV float bflo(unsigned u) { union { unsigned x; float f; } c; c.x = u << 16; return c.f; }
DEV float bfhi(unsigned u) { union { unsigned x; float f; } c; c.x = u & 0xffff0000u; return c.f; }

// ---------------- k_pre: BN1 sums straight from pts ----------------
__global__ __launch_bounds__(256) void k_pre(const float* __restrict__ pts,
                                             const float* __restrict__ Wp1,
                                             float* __restrict__ ws)
{
    __shared__ float red[4][4];
    const int t = threadIdx.x, w = t >> 6;
    const float wp10 = Wp1[0], wp11 = Wp1[1], wp12 = Wp1[2], wp13 = Wp1[3];
    float a[4] = {0.f, 0.f, 0.f, 0.f};
    #pragma unroll
    for (int it = 0; it < 4; ++it) {
        const int row = blockIdx.x * 1024 + it * 256 + t;
        const int n = row >> 4, j = row & 15;
        const int idxr = nbr_idx(n, j);
        const float2 pn = ((const float2*)pts)[n];
        const float2 pq = ((const float2*)pts)[idxr];
        const float tx = pq.x - pn.x, ty = pq.y - pn.y;
        const float p10 = wp10 * tx + wp11 * ty;
        const float p11 = wp12 * tx + wp13 * ty;
        a[0] += p10; a[1] += p11; a[2] += p10 * p10; a[3] += p11 * p11;
    }
    #pragma unroll
    for (int q = 0; q < 4; ++q) {
        float s = wave_sum(a[q]);
        if ((t & 63) == 0) red[w][q] = s;
    }
    __syncthreads();
    if (t < 4) atomicAdd(&ws[WS_SUM1 + t], red[0][t] + red[1][t] + red[2][t] + red[3][t]);
}

// ---------------- stage 1 (fused MFMA): trans/idx, e, energy, shrink, w1, BN2 partials ----
__global__ __launch_bounds__(256) void k_stage1(
    const float* __restrict__ pts, const float* __restrict__ feat,
    const float* __restrict__ W1, const float* __restrict__ b1,
    const float* __restrict__ Wb, const float* __restrict__ bb,
    const float* __restrict__ Wp1, const float* __restrict__ Wp2,
    const float* __restrict__ bp2, const float* __restrict__ gp,
    const float* __restrict__ bp, const float* __restrict__ W2a,
    float* __restrict__ out_trans, float* __restrict__ out_idx,
    float* __restrict__ ws)
{
    __shared__ float ts[4][16][2];
    __shared__ float es[4][16][36];     // cols 0..15: e / later w1-t0; 16..31: energy / w1-t1
    __shared__ float W1ts[32], b1s[16], bbs[16];
    __shared__ float sA0[16], sA1[16], sA2[16];
    __shared__ float red[4][64];

    const int t = threadIdx.x, w = t >> 6, l = t & 63, c0 = l & 15, jg = l >> 4;
    const int bid = blockIdx.x;
    const int n = ((bid & 7) * 1024 + (bid >> 3)) * 4 + w;   // XCD-bijective swizzle

    if (t < 32) W1ts[t] = W1[(t >> 1) * 66 + (t & 1)];
    if (t < 16) { b1s[t] = b1[t]; bbs[t] = bb[t]; }
    if (t >= 32 && t < 48) {            // shrink closed-form coefficients
        const int c = t - 32;
        float a0 = 0.f, a1 = 0.f, a2 = 0.f;
        for (int a8 = 0; a8 < 8; ++a8) {
            const int cc = a8 * 16 + c;
            a0 += Wp2[2 * cc]; a1 += Wp2[2 * cc + 1]; a2 += bp2[cc];
        }
        sA0[c] = a0; sA1[c] = a1; sA2[c] = a2;
    }

    // BN1 params (redundant per-thread; SUM1 finalized by k_pre)
    const float invM = 1.f / (float)NK;
    const float m0 = ws[WS_SUM1 + 0] * invM, m1 = ws[WS_SUM1 + 1] * invM;
    const float q0 = ws[WS_SUM1 + 2] * invM, q1 = ws[WS_SUM1 + 3] * invM;
    const float sc1x = gp[0] * rsqrtf(q0 - m0 * m0 + BN_EPS);
    const float sc1y = gp[1] * rsqrtf(q1 - m1 * m1 + BN_EPS);
    const float sh1x = fmaf(-m0, sc1x, bp[0]), sh1y = fmaf(-m1, sc1y, bp[1]);

    // weight B-frags
    bf16x8 w1b[2];
    #pragma unroll
    for (int kf = 0; kf < 2; ++kf) {
        const float* p = W1 + c0 * 66 + 2 + kf * 32 + jg * 8;
        const float2 v0 = *(const float2*)(p),     v1 = *(const float2*)(p + 2);
        const float2 v2 = *(const float2*)(p + 4), v3 = *(const float2*)(p + 6);
        w1b[kf] = cvt8(make_float4(v0.x, v0.y, v1.x, v1.y),
                       make_float4(v2.x, v2.y, v3.x, v3.y));
    }
    bf16x8 wbb[8];
    #pragma unroll
    for (int g = 0; g < 8; ++g) {
        const float4* p = (const float4*)(Wb + c0 * 256 + g * 32 + jg * 8);
        wbb[g] = cvt8(p[0], p[1]);
    }
    bf16x8 w2ab[2];
    #pragma unroll
    for (int tq = 0; tq < 2; ++tq) {
        const float4* p = (const float4*)(W2a + (c0 + 16 * tq) * 32 + jg * 8);
        w2ab[tq] = cvt8(p[0], p[1]);
    }

    // per-lane row j=c0
    const int idxr = nbr_idx(n, c0);
    const float2 pn = ((const float2*)pts)[n];
    const float2 pq = ((const float2*)pts)[idxr];
    const float tx = pq.x - pn.x, ty = pq.y - pn.y;
    if (jg == 0) {
        ts[w][c0][0] = tx; ts[w][c0][1] = ty;
        ((float2*)out_trans)[n * 16 + c0] = make_float2(tx, ty);
        out_idx[n * 16 + c0] = (float)idxr;
    }
    const float p10 = Wp1[0] * tx + Wp1[1] * ty;
    const float p11 = Wp1[2] * tx + Wp1[3] * ty;
    const float ph0 = fmaxf(fmaf(p10, sc1x, sh1x), 0.f);
    const float ph1 = fmaxf(fmaf(p11, sc1y, sh1y), 0.f);

    const float4* fb = (const float4*)(feat + (size_t)idxr * 64 + jg * 8);
    const bf16x8 fa0 = cvt8(fb[0], fb[1]);
    const bf16x8 fa1 = cvt8(fb[8], fb[9]);

    __syncthreads();    // B0: ts, sA, W1ts ready

    // e-tile
    f32x4 acc;
    #pragma unroll
    for (int r = 0; r < 4; ++r) {
        const int row = jg * 4 + r;
        acc[r] = b1s[c0] + W1ts[2 * c0] * ts[w][row][0] + W1ts[2 * c0 + 1] * ts[w][row][1];
    }
    acc = __builtin_amdgcn_mfma_f32_16x16x32_bf16(fa0, w1b[0], acc, 0, 0, 0);
    acc = __builtin_amdgcn_mfma_f32_16x16x32_bf16(fa1, w1b[1], acc, 0, 0, 0);
    #pragma unroll
    for (int r = 0; r < 4; ++r) es[w][jg * 4 + r][c0] = fmaxf(acc[r], 0.f);

    __syncthreads();    // B1: e-tile ready

    const float4 ef0 = *(const float4*)&es[w][c0][0];
    const float4 ef1 = *(const float4*)&es[w][c0][4];
    const float4 ef2 = *(const float4*)&es[w][c0][8];
    const float4 ef3 = *(const float4*)&es[w][c0][12];
    const float ev[16] = {ef0.x, ef0.y, ef0.z, ef0.w, ef1.x, ef1.y, ef1.z, ef1.w,
                          ef2.x, ef2.y, ef2.z, ef2.w, ef3.x, ef3.y, ef3.z, ef3.w};
    const bool hi = (jg & 1);
    const bool ih = (jg >> 1);
    float eh[8];
    #pragma unroll
    for (int e = 0; e < 8; ++e) eh[e] = hi ? ev[8 + e] : ev[e];

    f32x4 acc2;
    #pragma unroll
    for (int r = 0; r < 4; ++r) acc2[r] = bbs[c0];
    #pragma unroll
    for (int g = 0; g < 8; ++g) {
        const float ei = ih ? ev[2 * g + 1] : ev[2 * g];
        bf16x8 a2;
        #pragma unroll
        for (int e = 0; e < 8; ++e) a2[e] = (__bf16)(ei * eh[e]);
        acc2 = __builtin_amdgcn_mfma_f32_16x16x32_bf16(a2, wbb[g], acc2, 0, 0, 0);
    }
    // energy -> es cols 16..31 (disjoint from e reads)
    #pragma unroll
    for (int r = 0; r < 4; ++r) es[w][jg * 4 + r][16 + c0] = acc2[r];

    __syncthreads();    // B2: energy ready

    // x-frag for w1 GEMM: k=jg*8+e; k<16 energy, k>=16 shrink
    bf16x8 xa;
    if (jg < 2) {
        const float* src = &es[w][c0][16 + jg * 8];
        #pragma unroll
        for (int e = 0; e < 8; ++e) xa[e] = (__bf16)src[e];
    } else {
        const int off = (jg - 2) * 8;
        #pragma unroll
        for (int e = 0; e < 8; ++e)
            xa[e] = (__bf16)fmaf(ph0, sA0[off + e], fmaf(ph1, sA1[off + e], sA2[off + e]));
    }
    f32x4 z4 = {0.f, 0.f, 0.f, 0.f};
    f32x4 w1a0 = __builtin_amdgcn_mfma_f32_16x16x32_bf16(xa, w2ab[0], z4, 0, 0, 0);
    f32x4 w1a1 = __builtin_amdgcn_mfma_f32_16x16x32_bf16(xa, w2ab[1], z4, 0, 0, 0);

    // BN2 partials: sum over 16 rows per column
    float s10 = w1a0[0] + w1a0[1] + w1a0[2] + w1a0[3];
    float s11 = w1a1[0] + w1a1[1] + w1a1[2] + w1a1[3];
    float s20 = w1a0[0]*w1a0[0] + w1a0[1]*w1a0[1] + w1a0[2]*w1a0[2] + w1a0[3]*w1a0[3];
    float s21 = w1a1[0]*w1a1[0] + w1a1[1]*w1a1[1] + w1a1[2]*w1a1[2] + w1a1[3]*w1a1[3];
    #pragma unroll
    for (int off = 16; off <= 32; off <<= 1) {
        s10 += __shfl_xor(s10, off); s11 += __shfl_xor(s11, off);
        s20 += __shfl_xor(s20, off); s21 += __shfl_xor(s21, off);
    }
    if (jg == 0) {
        red[w][c0] = s10; red[w][16 + c0] = s11;
        red[w][32 + c0] = s20; red[w][48 + c0] = s21;
    }

    __syncthreads();    // B3: all x-frag reads done, red written

    // w1 -> es (cols 0..31), then pack to bf16 + coalesced store
    #pragma unroll
    for (int r = 0; r < 4; ++r) {
        es[w][jg * 4 + r][c0]      = w1a0[r];
        es[w][jg * 4 + r][16 + c0] = w1a1[r];
    }
    __syncthreads();    // B4

    {
        const int row = l >> 2, ch = l & 3;
        const float* src = &es[w][row][ch * 8];
        bf16x8 pk;
        #pragma unroll
        for (int e = 0; e < 8; ++e) pk[e] = (__bf16)src[e];
        bf16x8* w1v = reinterpret_cast<bf16x8*>(ws + WS_W1);
        w1v[(size_t)(n * 16 + row) * 4 + ch] = pk;
    }
    if (t < 64) {
        float* P = ws + WS_P2;
        P[(size_t)bid * 64 + t] = red[0][t] + red[1][t] + red[2][t] + red[3][t];
    }
}

// ---------------- k_red2: BN2 partials -> SUM2 ----------------
__global__ __launch_bounds__(256) void k_red2(float* __restrict__ ws)
{
    __shared__ float red[4][64];
    const int t = threadIdx.x, c = t & 63, g = t >> 6;
    const float* P = ws + WS_P2;
    float s = 0.f;
    for (int r = blockIdx.x * 256 + g; r < (blockIdx.x + 1) * 256; r += 4)
        s += P[(size_t)r * 64 + c];
    red[g][c] = s;
    __syncthreads();
    if (t < 64) atomicAdd(&ws[WS_SUM2 + t], red[0][t] + red[1][t] + red[2][t] + red[3][t]);
}

// ---------------- stage 3: w1 -> w2, BN3 sums ----------------
__global__ __launch_bounds__(256) void k_stage3(
    const float* __restrict__ g2a, const float* __restrict__ b2a,
    const float* __restrict__ W2b, float* __restrict__ ws)
{
    __shared__ float sc2s[32], sh2s[32], w2bs[128];
    __shared__ float red[4][8];
    const int t = threadIdx.x, w = t >> 6, l = t & 63;
    if (t < 32) {
        const float invM = 1.f / (float)NK;
        const float m = ws[WS_SUM2 + t] * invM, q = ws[WS_SUM2 + 32 + t] * invM;
        const float sc = g2a[t] * rsqrtf(q - m * m + BN_EPS);
        sc2s[t] = sc; sh2s[t] = fmaf(-m, sc, b2a[t]);
    }
    if (t < 128) w2bs[t] = W2b[t];
    __syncthreads();

    const size_t row = (size_t)blockIdx.x * 256 + t;
    const uint4* w1u = reinterpret_cast<const uint4*>(ws + WS_W1) + row * 4;
    float h[32];
    #pragma unroll
    for (int i = 0; i < 4; ++i) {
        const uint4 u = w1u[i];
        h[i*8+0] = bflo(u.x); h[i*8+1] = bfhi(u.x);
        h[i*8+2] = bflo(u.y); h[i*8+3] = bfhi(u.y);
        h[i*8+4] = bflo(u.z); h[i*8+5] = bfhi(u.z);
        h[i*8+6] = bflo(u.w); h[i*8+7] = bfhi(u.w);
    }
    float acc[4] = {0.f, 0.f, 0.f, 0.f};
    #pragma unroll
    for (int q = 0; q < 32; ++q) {
        const float hv = fmaxf(fmaf(h[q], sc2s[q], sh2s[q]), 0.f);
        #pragma unroll
        for (int p = 0; p < 4; ++p) acc[p] = fmaf(w2bs[p * 32 + q], hv, acc[p]);
    }
    ((float4*)(ws + WS_W2))[row] = make_float4(acc[0], acc[1], acc[2], acc[3]);

    float r8[8] = {acc[0], acc[1], acc[2], acc[3],
                   acc[0]*acc[0], acc[1]*acc[1], acc[2]*acc[2], acc[3]*acc[3]};
    #pragma unroll
    for (int i = 0; i < 8; ++i) r8[i] = wave_sum(r8[i]);
    if (l == 0) {
        #pragma unroll
        for (int i = 0; i < 8; ++i) red[w][i] = r8[i];
    }
    __syncthreads();
    if (t < 8) atomicAdd(&ws[WS_SUM3 + t], red[0][t] + red[1][t] + red[2][t] + red[3][t]);
}

// ---------------- stage 4 (transposed MFMA): softmax + v-matmul + combine ----------------
// D'[cc][j] = (W3 . F^T): A-frags = W3 rows, B-frags = gathered feat rows.
// Lane (jg,c0): rows cc=16s+jg*4+r, col j=c0  ->  float4 stores of 4 consecutive cols.
__global__ __launch_bounds__(256) void k_stage4(
    const float* __restrict__ feat, const float* __restrict__ Wp1,
    const float* __restrict__ Wp2, const float* __restrict__ bp2,
    const float* __restrict__ W2c, const float* __restrict__ b2c,
    const float* __restrict__ W3, const float* __restrict__ b3,
    const float* __restrict__ gp, const float* __restrict__ bp,
    const float* __restrict__ g2b, const float* __restrict__ b2b,
    const float* __restrict__ out_trans, const float* __restrict__ ws,
    float* __restrict__ out)
{
    __shared__ float wp2a[COUT], wp2b[COUT], pb3[COUT], w2cs[64], b2cs[16];

    const int t = threadIdx.x, w = t >> 6, l = t & 63, c0 = l & 15, jg = l >> 4;
    const int bid = blockIdx.x;
    const int n = ((bid & 7) * 1024 + (bid >> 3)) * 4 + w;   // XCD-bijective swizzle

    for (int x = t; x < COUT; x += 256) {
        wp2a[x] = Wp2[2 * x]; wp2b[x] = Wp2[2 * x + 1]; pb3[x] = bp2[x] + b3[x];
    }
    if (t < 64) w2cs[t] = W2c[t];
    if (t < 16) b2cs[t] = b2c[t];

    // BN1 + BN3 params per-thread
    const float invM = 1.f / (float)NK;
    const float m0 = ws[WS_SUM1 + 0] * invM, m1 = ws[WS_SUM1 + 1] * invM;
    const float q0 = ws[WS_SUM1 + 2] * invM, q1 = ws[WS_SUM1 + 3] * invM;
    const float sc1x = gp[0] * rsqrtf(q0 - m0 * m0 + BN_EPS);
    const float sc1y = gp[1] * rsqrtf(q1 - m1 * m1 + BN_EPS);
    const float sh1x = fmaf(-m0, sc1x, bp[0]), sh1y = fmaf(-m1, sc1y, bp[1]);
    float sc3[4], sh3[4];
    #pragma unroll
    for (int p = 0; p < 4; ++p) {
        const float m = ws[WS_SUM3 + p] * invM, q = ws[WS_SUM3 + 4 + p] * invM;
        sc3[p] = g2b[p] * rsqrtf(q - m * m + BN_EPS);
        sh3[p] = fmaf(-m, sc3[p], b2b[p]);
    }

    // A-frags: W3 rows cc=16s+c0, k=jg*8+e (+32)
    bf16x8 w3a[16];
    #pragma unroll
    for (int s = 0; s < 8; ++s) {
        const float* rowp = W3 + (size_t)(16 * s + c0) * 64 + jg * 8;
        const float4* p0 = (const float4*)rowp;
        const float4* p1 = (const float4*)(rowp + 32);
        w3a[2 * s]     = cvt8(p0[0], p0[1]);
        w3a[2 * s + 1] = cvt8(p1[0], p1[1]);
    }
    // B-frags: gathered feat row j=c0
    const int idxr = nbr_idx(n, c0);
    const float4* fb = (const float4*)(feat + (size_t)idxr * 64 + jg * 8);
    const bf16x8 fa0 = cvt8(fb[0], fb[1]);
    const bf16x8 fa1 = cvt8(fb[8], fb[9]);

    // p-path for row j=c0
    const float2 tr = ((const float2*)out_trans)[n * 16 + c0];
    const float p10 = Wp1[0] * tr.x + Wp1[1] * tr.y;
    const float p11 = Wp1[2] * tr.x + Wp1[3] * tr.y;
    const float ph0 = fmaxf(fmaf(p10, sc1x, sh1x), 0.f);
    const float ph1 = fmaxf(fmaf(p11, sc1y, sh1y), 0.f);

    __syncthreads();

    // logits + softmax over j (= c0 lanes) per channel c=jg*4+r
    const float4 qv = ((const float4*)(ws + WS_W2))[n * 16 + c0];
    const float h0 = fmaxf(fmaf(qv.x, sc3[0], sh3[0]), 0.f);
    const float h1 = fmaxf(fmaf(qv.y, sc3[1], sh3[1]), 0.f);
    const float h2 = fmaxf(fmaf(qv.z, sc3[2], sh3[2]), 0.f);
    const float h3 = fmaxf(fmaf(qv.w, sc3[3], sh3[3]), 0.f);
    float wsm[4];
    #pragma unroll
    for (int r = 0; r < 4; ++r) {
        const int c = jg * 4 + r;
        const float lgv = b2cs[c] + w2cs[c*4]*h0 + w2cs[c*4+1]*h1
                        + w2cs[c*4+2]*h2 + w2cs[c*4+3]*h3;
        float mx = lgv;
        #pragma unroll
        for (int off = 1; off <= 8; off <<= 1) mx = fmaxf(mx, __shfl_xor(mx, off));
        const float ex = __expf(lgv - mx);
        float ss = ex;
        #pragma unroll
        for (int off = 1; off <= 8; off <<= 1) ss += __shfl_xor(ss, off);
        wsm[r] = ex / ss;
    }

    // C-init = b3 + bp2 + p_embed  (rows cc, col j=c0)
    f32x4 accs[8];
    #pragma unroll
    for (int s = 0; s < 8; ++s) {
        #pragma unroll
        for (int r = 0; r < 4; ++r) {
            const int cc = 16 * s + jg * 4 + r;
            accs[s][r] = fmaf(ph0, wp2a[cc], fmaf(ph1, wp2b[cc], pb3[cc]));
        }
    }
    #pragma unroll
    for (int s = 0; s < 8; ++s) {
        accs[s] = __builtin_amdgcn_mfma_f32_16x16x32_bf16(w3a[2*s],   fa0, accs[s], 0, 0, 0);
        accs[s] = __builtin_amdgcn_mfma_f32_16x16x32_bf16(w3a[2*s+1], fa1, accs[s], 0, 0, 0);
    }

    float* ob = out + (size_t)(n * 16 + c0) * COUT;
    #pragma unroll
    for (int s = 0; s < 8; ++s) {
        const float4 o4 = make_float4(accs[s][0] * wsm[0], accs[s][1] * wsm[1],
                                      accs[s][2] * wsm[2], accs[s][3] * wsm[3]);
        *(float4*)(ob + 16 * s + jg * 4) = o4;
    }
}

extern "C" void kernel_launch(void* const* d_in, const int* in_sizes, int n_in,
                              void* d_out, int out_size, void* d_ws, size_t ws_size,
                              hipStream_t stream)
{
    const float* pts  = (const float*)d_in[0];
    const float* feat = (const float*)d_in[1];
    const float* W1   = (const float*)d_in[2];
    const float* b1   = (const float*)d_in[3];
    const float* Wb   = (const float*)d_in[4];
    const float* bb   = (const float*)d_in[5];
    const float* Wp1  = (const float*)d_in[6];
    const float* gp   = (const float*)d_in[7];
    const float* bp   = (const float*)d_in[8];
    const float* Wp2  = (const float*)d_in[9];
    const float* bp2  = (const float*)d_in[10];
    const float* W2a  = (const float*)d_in[11];
    const float* g2a  = (const float*)d_in[12];
    const float* b2a  = (const float*)d_in[13];
    const float* W2b  = (const float*)d_in[14];
    const float* g2b  = (const float*)d_in[15];
    const float* b2b  = (const float*)d_in[16];
    const float* W2c  = (const float*)d_in[17];
    const float* b2c  = (const float*)d_in[18];
    const float* W3   = (const float*)d_in[19];
    const float* b3   = (const float*)d_in[20];

    float* out       = (float*)d_out;
    float* out_trans = out + (size_t)NK * COUT;
    float* out_idx   = out_trans + (size_t)NK * 2;
    float* ws        = (float*)d_ws;

    hipMemsetAsync(ws, 0, 256 * sizeof(float), stream);
    k_pre<<<512, 256, 0, stream>>>(pts, Wp1, ws);
    k_stage1<<<8192, 256, 0, stream>>>(pts, feat, W1, b1, Wb, bb, Wp1, Wp2, bp2,
                                       gp, bp, W2a, out_trans, out_idx, ws);
    k_red2<<<32, 256, 0, stream>>>(ws);
    k_stage3<<<2048, 256, 0, stream>>>(g2a, b2a, W2b, ws);
    k_stage4<<<8192, 256, 0, stream>>>(feat, Wp1, Wp2, bp2, W2c, b2c, W3, b3,
                                       gp, bp, g2b, b2b, out_trans, ws, out);
}

// Round 5
// 260.232 us; speedup vs baseline: 8.6160x; 1.3725x over previous
//
#include <hip/hip_runtime.h>

#define DEV static __device__ __forceinline__

namespace {
constexpr int PB   = 4096;
constexpr int NPTS = 32768;
constexpr int RR   = 8;
constexpr int K    = 16;
constexpr int COUT = 128;
constexpr int NK   = NPTS * K;    // 524288
constexpr float BN_EPS = 1e-5f;

// ws float offsets
constexpr int    WS_SUM1 = 0;                         // 4
constexpr int    WS_SUM2 = 4;                         // 64
constexpr int    WS_SUM3 = 68;                        // 8
constexpr size_t WS_P2   = 256;                       // 2048*64 f32 BN2 block partials
constexpr size_t WS_W1   = WS_P2 + 2048 * 64;         // NK*32 bf16 (= NK*16 f32-equiv)
constexpr size_t WS_W2   = WS_W1 + (size_t)NK * 16;   // NK*4 f32
}

typedef __attribute__((ext_vector_type(8))) __bf16 bf16x8;
typedef __attribute__((ext_vector_type(4))) float  f32x4;

DEV int nbr_idx(int n, int j) {
    int b = n >> 12, i = n & (PB - 1);
    int o = (j < RR) ? (j - RR) : (j - RR + 1);
    return (b << 12) | ((i + o + PB) & (PB - 1));
}
DEV float wave_sum(float v) {
    #pragma unroll
    for (int off = 32; off >= 1; off >>= 1) v += __shfl_xor(v, off);
    return v;
}
DEV bf16x8 cvt8(float4 a, float4 b) {
    bf16x8 r;
    r[0] = (__bf16)a.x; r[1] = (__bf16)a.y; r[2] = (__bf16)a.z; r[3] = (__bf16)a.w;
    r[4] = (__bf16)b.x; r[5] = (__bf16)b.y; r[6] = (__bf16)b.z; r[7] = (__bf16)b.w;
    return r;
}
DEV float bflo(unsigned u) { union { unsigned x; float f; } c; c.x = u << 16; return c.f; }
DEV float bfhi(unsigned u) { union { unsigned x; float f; } c; c.x = u & 0xffff0000u; return c.f; }
// wave-local LDS fence: all prior DS ops complete; nothing reorders across (rule #18)
DEV void wave_fence() {
    asm volatile("s_waitcnt lgkmcnt(0)" ::: "memory");
    __builtin_amdgcn_sched_barrier(0);
}

// ---------------- k_pre: BN1 sums straight from pts ----------------
__global__ __launch_bounds__(256) void k_pre(const float* __restrict__ pts,
                                             const float* __restrict__ Wp1,
                                             float* __restrict__ ws)
{
    __shared__ float red[4][4];
    const int t = threadIdx.x, w = t >> 6;
    const float wp10 = Wp1[0], wp11 = Wp1[1], wp12 = Wp1[2], wp13 = Wp1[3];
    float a[4] = {0.f, 0.f, 0.f, 0.f};
    #pragma unroll
    for (int it = 0; it < 4; ++it) {
        const int row = blockIdx.x * 1024 + it * 256 + t;
        const int n = row >> 4, j = row & 15;
        const int idxr = nbr_idx(n, j);
        const float2 pn = ((const float2*)pts)[n];
        const float2 pq = ((const float2*)pts)[idxr];
        const float tx = pq.x - pn.x, ty = pq.y - pn.y;
        const float p10 = wp10 * tx + wp11 * ty;
        const float p11 = wp12 * tx + wp13 * ty;
        a[0] += p10; a[1] += p11; a[2] += p10 * p10; a[3] += p11 * p11;
    }
    #pragma unroll
    for (int q = 0; q < 4; ++q) {
        float s = wave_sum(a[q]);
        if ((t & 63) == 0) red[w][q] = s;
    }
    __syncthreads();
    if (t < 4) atomicAdd(&ws[WS_SUM1 + t], red[0][t] + red[1][t] + red[2][t] + red[3][t]);
}

// ---------------- stage 1 (fused MFMA, 4n/wave): trans/idx, e, energy, shrink, w1, BN2 ----
__global__ __launch_bounds__(256) void k_stage1(
    const float* __restrict__ pts, const float* __restrict__ feat,
    const float* __restrict__ W1, const float* __restrict__ b1,
    const float* __restrict__ Wb, const float* __restrict__ bb,
    const float* __restrict__ Wp1, const float* __restrict__ Wp2,
    const float* __restrict__ bp2, const float* __restrict__ gp,
    const float* __restrict__ bp, const float* __restrict__ W2a,
    float* __restrict__ out_trans, float* __restrict__ out_idx,
    float* __restrict__ ws)
{
    __shared__ float es[4][16][36];     // per-wave tile (stride 36 floats = 144B, 16B-aligned)
    __shared__ float sA0[16], sA1[16], sA2[16];
    __shared__ float red[4][64];

    const int t = threadIdx.x, w = t >> 6, l = t & 63, c0 = l & 15, jg = l >> 4;
    const int bid = blockIdx.x;
    const int n0 = ((bid & 7) * 256 + (bid >> 3)) * 16 + w * 4;  // XCD-bijective swizzle

    if (t < 16) {                       // shrink closed-form coefficients
        float a0 = 0.f, a1 = 0.f, a2 = 0.f;
        for (int a8 = 0; a8 < 8; ++a8) {
            const int cc = a8 * 16 + t;
            a0 += Wp2[2 * cc]; a1 += Wp2[2 * cc + 1]; a2 += bp2[cc];
        }
        sA0[t] = a0; sA1[t] = a1; sA2[t] = a2;
    }

    // BN1 params (per-thread; SUM1 from k_pre)
    const float invM = 1.f / (float)NK;
    const float m0 = ws[WS_SUM1 + 0] * invM, m1 = ws[WS_SUM1 + 1] * invM;
    const float q0 = ws[WS_SUM1 + 2] * invM, q1 = ws[WS_SUM1 + 3] * invM;
    const float sc1x = gp[0] * rsqrtf(q0 - m0 * m0 + BN_EPS);
    const float sc1y = gp[1] * rsqrtf(q1 - m1 * m1 + BN_EPS);
    const float sh1x = fmaf(-m0, sc1x, bp[0]), sh1y = fmaf(-m1, sc1y, bp[1]);
    const float wp10 = Wp1[0], wp11 = Wp1[1], wp12 = Wp1[2], wp13 = Wp1[3];

    // wave-persistent weights (loaded once, reused for 4 n)
    const float w1cx = W1[c0 * 66], w1cy = W1[c0 * 66 + 1];
    const float b1c = b1[c0], bbc = bb[c0];
    bf16x8 w1b[2];
    #pragma unroll
    for (int kf = 0; kf < 2; ++kf) {
        const float* p = W1 + c0 * 66 + 2 + kf * 32 + jg * 8;
        const float2 v0 = *(const float2*)(p),     v1 = *(const float2*)(p + 2);
        const float2 v2 = *(const float2*)(p + 4), v3 = *(const float2*)(p + 6);
        w1b[kf] = cvt8(make_float4(v0.x, v0.y, v1.x, v1.y),
                       make_float4(v2.x, v2.y, v3.x, v3.y));
    }
    bf16x8 wbb[8];
    #pragma unroll
    for (int g = 0; g < 8; ++g) {
        const float4* p = (const float4*)(Wb + c0 * 256 + g * 32 + jg * 8);
        wbb[g] = cvt8(p[0], p[1]);
    }
    bf16x8 w2ab[2];
    #pragma unroll
    for (int tq = 0; tq < 2; ++tq) {
        const float4* p = (const float4*)(W2a + (c0 + 16 * tq) * 32 + jg * 8);
        w2ab[tq] = cvt8(p[0], p[1]);
    }

    // per-n prefetch (all loads independent -> overlapped latency)
    int idxr[4]; float txv[4], tyv[4], ph0v[4], ph1v[4];
    bf16x8 fa0[4], fa1[4];
    #pragma unroll
    for (int nn = 0; nn < 4; ++nn) {
        const int n = n0 + nn;
        idxr[nn] = nbr_idx(n, c0);
        const float2 pn = ((const float2*)pts)[n];
        const float2 pq = ((const float2*)pts)[idxr[nn]];
        txv[nn] = pq.x - pn.x; tyv[nn] = pq.y - pn.y;
        const float p10 = wp10 * txv[nn] + wp11 * tyv[nn];
        const float p11 = wp12 * txv[nn] + wp13 * tyv[nn];
        ph0v[nn] = fmaxf(fmaf(p10, sc1x, sh1x), 0.f);
        ph1v[nn] = fmaxf(fmaf(p11, sc1y, sh1y), 0.f);
        const float4* fb = (const float4*)(feat + (size_t)idxr[nn] * 64 + jg * 8);
        fa0[nn] = cvt8(fb[0], fb[1]);
        fa1[nn] = cvt8(fb[8], fb[9]);
        if (jg == 0) {
            ((float2*)out_trans)[n * 16 + c0] = make_float2(txv[nn], tyv[nn]);
            out_idx[n * 16 + c0] = (float)idxr[nn];
        }
    }

    float s10 = 0.f, s11 = 0.f, s20 = 0.f, s21 = 0.f;
    __syncthreads();    // sA ready

    #pragma unroll
    for (int nn = 0; nn < 4; ++nn) {
        // e-tile: C-init via shfl-transposed trans, 2 MFMAs over feat
        f32x4 acc;
        #pragma unroll
        for (int r = 0; r < 4; ++r) {
            const int row = jg * 4 + r;
            const float trx = __shfl(txv[nn], row);
            const float tryv = __shfl(tyv[nn], row);
            acc[r] = b1c + w1cx * trx + w1cy * tryv;
        }
        acc = __builtin_amdgcn_mfma_f32_16x16x32_bf16(fa0[nn], w1b[0], acc, 0, 0, 0);
        acc = __builtin_amdgcn_mfma_f32_16x16x32_bf16(fa1[nn], w1b[1], acc, 0, 0, 0);
        #pragma unroll
        for (int r = 0; r < 4; ++r) es[w][jg * 4 + r][c0] = fmaxf(acc[r], 0.f);
        wave_fence();

        // bilinear: lane reads e row c0, forms E2 frags in-register
        const float4 ef0 = *(const float4*)&es[w][c0][0];
        const float4 ef1 = *(const float4*)&es[w][c0][4];
        const float4 ef2 = *(const float4*)&es[w][c0][8];
        const float4 ef3 = *(const float4*)&es[w][c0][12];
        const float ev[16] = {ef0.x, ef0.y, ef0.z, ef0.w, ef1.x, ef1.y, ef1.z, ef1.w,
                              ef2.x, ef2.y, ef2.z, ef2.w, ef3.x, ef3.y, ef3.z, ef3.w};
        const bool hi = (jg & 1);
        const bool ih = (jg >> 1);
        float eh[8];
        #pragma unroll
        for (int e = 0; e < 8; ++e) eh[e] = hi ? ev[8 + e] : ev[e];
        f32x4 acc2;
        #pragma unroll
        for (int r = 0; r < 4; ++r) acc2[r] = bbc;
        #pragma unroll
        for (int g = 0; g < 8; ++g) {
            const float ei = ih ? ev[2 * g + 1] : ev[2 * g];
            bf16x8 a2;
            #pragma unroll
            for (int e = 0; e < 8; ++e) a2[e] = (__bf16)(ei * eh[e]);
            acc2 = __builtin_amdgcn_mfma_f32_16x16x32_bf16(a2, wbb[g], acc2, 0, 0, 0);
        }
        #pragma unroll
        for (int r = 0; r < 4; ++r) es[w][jg * 4 + r][16 + c0] = acc2[r];
        wave_fence();

        // x-frag: k<16 energy (LDS), k>=16 shrink (closed form)
        bf16x8 xa;
        if (jg < 2) {
            const float* src = &es[w][c0][16 + jg * 8];
            #pragma unroll
            for (int e = 0; e < 8; ++e) xa[e] = (__bf16)src[e];
        } else {
            const int off = (jg - 2) * 8;
            #pragma unroll
            for (int e = 0; e < 8; ++e)
                xa[e] = (__bf16)fmaf(ph0v[nn], sA0[off + e],
                                     fmaf(ph1v[nn], sA1[off + e], sA2[off + e]));
        }
        const f32x4 z4 = {0.f, 0.f, 0.f, 0.f};
        f32x4 w1a0 = __builtin_amdgcn_mfma_f32_16x16x32_bf16(xa, w2ab[0], z4, 0, 0, 0);
        f32x4 w1a1 = __builtin_amdgcn_mfma_f32_16x16x32_bf16(xa, w2ab[1], z4, 0, 0, 0);
        #pragma unroll
        for (int r = 0; r < 4; ++r) {
            s10 += w1a0[r]; s20 += w1a0[r] * w1a0[r];
            s11 += w1a1[r]; s21 += w1a1[r] * w1a1[r];
        }
        wave_fence();   // all x-frag energy reads complete before overwrite

        #pragma unroll
        for (int r = 0; r < 4; ++r) {
            es[w][jg * 4 + r][c0]      = w1a0[r];
            es[w][jg * 4 + r][16 + c0] = w1a1[r];
        }
        wave_fence();

        // pack w1 -> bf16, coalesced store
        {
            const int row = l >> 2, ch = l & 3;
            const float* src = &es[w][row][ch * 8];
            bf16x8 pk;
            #pragma unroll
            for (int e = 0; e < 8; ++e) pk[e] = (__bf16)src[e];
            reinterpret_cast<bf16x8*>(ws + WS_W1)[(size_t)((n0 + nn) * 16 + row) * 4 + ch] = pk;
        }
        wave_fence();   // pack reads complete before next-iter e writes
    }

    // BN2 block partials (one gmem write per block)
    #pragma unroll
    for (int off = 16; off <= 32; off <<= 1) {
        s10 += __shfl_xor(s10, off); s11 += __shfl_xor(s11, off);
        s20 += __shfl_xor(s20, off); s21 += __shfl_xor(s21, off);
    }
    if (jg == 0) {
        red[w][c0] = s10; red[w][16 + c0] = s11;
        red[w][32 + c0] = s20; red[w][48 + c0] = s21;
    }
    __syncthreads();
    if (t < 64)
        (ws + WS_P2)[(size_t)bid * 64 + t] = red[0][t] + red[1][t] + red[2][t] + red[3][t];
}

// ---------------- k_red2: BN2 partials -> SUM2 ----------------
__global__ __launch_bounds__(256) void k_red2(float* __restrict__ ws)
{
    __shared__ float red[4][64];
    const int t = threadIdx.x, c = t & 63, g = t >> 6;
    const float* P = ws + WS_P2;
    float s = 0.f;
    for (int r = blockIdx.x * 256 + g; r < (blockIdx.x + 1) * 256; r += 4)
        s += P[(size_t)r * 64 + c];
    red[g][c] = s;
    __syncthreads();
    if (t < 64) atomicAdd(&ws[WS_SUM2 + t], red[0][t] + red[1][t] + red[2][t] + red[3][t]);
}

// ---------------- stage 3: w1 -> w2, BN3 sums ----------------
__global__ __launch_bounds__(256) void k_stage3(
    const float* __restrict__ g2a, const float* __restrict__ b2a,
    const float* __restrict__ W2b, float* __restrict__ ws)
{
    __shared__ float sc2s[32], sh2s[32], w2bs[128];
    __shared__ float red[4][8];
    const int t = threadIdx.x, w = t >> 6, l = t & 63;
    if (t < 32) {
        const float invM = 1.f / (float)NK;
        const float m = ws[WS_SUM2 + t] * invM, q = ws[WS_SUM2 + 32 + t] * invM;
        const float sc = g2a[t] * rsqrtf(q - m * m + BN_EPS);
        sc2s[t] = sc; sh2s[t] = fmaf(-m, sc, b2a[t]);
    }
    if (t < 128) w2bs[t] = W2b[t];
    __syncthreads();

    const size_t row = (size_t)blockIdx.x * 256 + t;
    const uint4* w1u = reinterpret_cast<const uint4*>(ws + WS_W1) + row * 4;
    float h[32];
    #pragma unroll
    for (int i = 0; i < 4; ++i) {
        const uint4 u = w1u[i];
        h[i*8+0] = bflo(u.x); h[i*8+1] = bfhi(u.x);
        h[i*8+2] = bflo(u.y); h[i*8+3] = bfhi(u.y);
        h[i*8+4] = bflo(u.z); h[i*8+5] = bfhi(u.z);
        h[i*8+6] = bflo(u.w); h[i*8+7] = bfhi(u.w);
    }
    float acc[4] = {0.f, 0.f, 0.f, 0.f};
    #pragma unroll
    for (int q = 0; q < 32; ++q) {
        const float hv = fmaxf(fmaf(h[q], sc2s[q], sh2s[q]), 0.f);
        #pragma unroll
        for (int p = 0; p < 4; ++p) acc[p] = fmaf(w2bs[p * 32 + q], hv, acc[p]);
    }
    ((float4*)(ws + WS_W2))[row] = make_float4(acc[0], acc[1], acc[2], acc[3]);

    float r8[8] = {acc[0], acc[1], acc[2], acc[3],
                   acc[0]*acc[0], acc[1]*acc[1], acc[2]*acc[2], acc[3]*acc[3]};
    #pragma unroll
    for (int i = 0; i < 8; ++i) r8[i] = wave_sum(r8[i]);
    if (l == 0) {
        #pragma unroll
        for (int i = 0; i < 8; ++i) red[w][i] = r8[i];
    }
    __syncthreads();
    if (t < 8) atomicAdd(&ws[WS_SUM3 + t], red[0][t] + red[1][t] + red[2][t] + red[3][t]);
}

// ---------------- stage 4 (MFMA, W3 in LDS, 4n/wave) ----------------
__global__ __launch_bounds__(256) void k_stage4(
    const float* __restrict__ feat, const float* __restrict__ Wp1,
    const float* __restrict__ Wp2, const float* __restrict__ bp2,
    const float* __restrict__ W2c, const float* __restrict__ b2c,
    const float* __restrict__ W3, const float* __restrict__ b3,
    const float* __restrict__ gp, const float* __restrict__ bp,
    const float* __restrict__ g2b, const float* __restrict__ b2b,
    const float* __restrict__ out_trans, const float* __restrict__ ws,
    float* __restrict__ out)
{
    __shared__ bf16x8 w3lds[1024];      // frag (s,kf,l): lane-contiguous -> conflict-free b128
    __shared__ float4 pA[32], pB[32], pC[32];   // epilogue coeffs, idx = s*4+jg, comp = r
    __shared__ float4 w2c4[16];
    __shared__ float  b2cs[16];

    const int t = threadIdx.x, w = t >> 6, l = t & 63, c0 = l & 15, jg = l >> 4;
    const int bid = blockIdx.x;
    const int n0 = ((bid & 7) * 256 + (bid >> 3)) * 16 + w * 4;  // XCD-bijective swizzle

    for (int f = t; f < 1024; f += 256) {
        const int s = f >> 7, kf = (f >> 6) & 1, l2 = f & 63;
        const float4* p = (const float4*)(W3 + (size_t)(16 * s + (l2 & 15)) * 64
                                          + kf * 32 + (l2 >> 4) * 8);
        w3lds[f] = cvt8(p[0], p[1]);
    }
    if (t < 32) {
        const int s = t >> 2, cc = 16 * s + (t & 3) * 4;
        pA[t] = make_float4(Wp2[2*cc], Wp2[2*cc+2], Wp2[2*cc+4], Wp2[2*cc+6]);
        pB[t] = make_float4(Wp2[2*cc+1], Wp2[2*cc+3], Wp2[2*cc+5], Wp2[2*cc+7]);
        pC[t] = make_float4(bp2[cc] + b3[cc], bp2[cc+1] + b3[cc+1],
                            bp2[cc+2] + b3[cc+2], bp2[cc+3] + b3[cc+3]);
    }
    if (t < 16) {
        w2c4[t] = make_float4(W2c[4*t], W2c[4*t+1], W2c[4*t+2], W2c[4*t+3]);
        b2cs[t] = b2c[t];
    }

    // BN1 + BN3 params per-thread
    const float invM = 1.f / (float)NK;
    const float m0 = ws[WS_SUM1 + 0] * invM, m1 = ws[WS_SUM1 + 1] * invM;
    const float q0 = ws[WS_SUM1 + 2] * invM, q1 = ws[WS_SUM1 + 3] * invM;
    const float sc1x = gp[0] * rsqrtf(q0 - m0 * m0 + BN_EPS);
    const float sc1y = gp[1] * rsqrtf(q1 - m1 * m1 + BN_EPS);
    const float sh1x = fmaf(-m0, sc1x, bp[0]), sh1y = fmaf(-m1, sc1y, bp[1]);
    const float wp10 = Wp1[0], wp11 = Wp1[1], wp12 = Wp1[2], wp13 = Wp1[3];
    float sc3[4], sh3[4];
    #pragma unroll
    for (int p = 0; p < 4; ++p) {
        const float m = ws[WS_SUM3 + p] * invM, q = ws[WS_SUM3 + 4 + p] * invM;
        sc3[p] = g2b[p] * rsqrtf(q - m * m + BN_EPS);
        sh3[p] = fmaf(-m, sc3[p], b2b[p]);
    }

    // prefetch all per-n inputs for 4 n
    int idxr[4]; float2 trv[4]; float4 qv[4];
    bf16x8 fa0[4], fa1[4];
    #pragma unroll
    for (int nn = 0; nn < 4; ++nn) {
        const int n = n0 + nn;
        idxr[nn] = nbr_idx(n, c0);
        const float4* fb = (const float4*)(feat + (size_t)idxr[nn] * 64 + jg * 8);
        fa0[nn] = cvt8(fb[0], fb[1]);
        fa1[nn] = cvt8(fb[8], fb[9]);
        trv[nn] = ((const float2*)out_trans)[n * 16 + c0];
        qv[nn]  = ((const float4*)(ws + WS_W2))[n * 16 + c0];
    }
    __syncthreads();

    #pragma unroll
    for (int nn = 0; nn < 4; ++nn) {
        const int n = n0 + nn;
        // p-path for row j=c0
        const float p10 = wp10 * trv[nn].x + wp11 * trv[nn].y;
        const float p11 = wp12 * trv[nn].x + wp13 * trv[nn].y;
        const float ph0 = fmaxf(fmaf(p10, sc1x, sh1x), 0.f);
        const float ph1 = fmaxf(fmaf(p11, sc1y, sh1y), 0.f);
        // softmax over j (c0 lanes) per channel c=jg*4+r
        const float h0 = fmaxf(fmaf(qv[nn].x, sc3[0], sh3[0]), 0.f);
        const float h1 = fmaxf(fmaf(qv[nn].y, sc3[1], sh3[1]), 0.f);
        const float h2 = fmaxf(fmaf(qv[nn].z, sc3[2], sh3[2]), 0.f);
        const float h3 = fmaxf(fmaf(qv[nn].w, sc3[3], sh3[3]), 0.f);
        float wsm[4];
        #pragma unroll
        for (int r = 0; r < 4; ++r) {
            const int c = jg * 4 + r;
            const float4 wc = w2c4[c];
            const float lgv = b2cs[c] + wc.x * h0 + wc.y * h1 + wc.z * h2 + wc.w * h3;
            float mx = lgv;
            #pragma unroll
            for (int off = 1; off <= 8; off <<= 1) mx = fmaxf(mx, __shfl_xor(mx, off));
            const float ex = __expf(lgv - mx);
            float ss = ex;
            #pragma unroll
            for (int off = 1; off <= 8; off <<= 1) ss += __shfl_xor(ss, off);
            wsm[r] = ex / ss;
        }
        // matmul + epilogue: rows cc=16s+jg*4+r, col j=c0
        float* ob = out + (size_t)(n * 16 + c0) * COUT;
        #pragma unroll
        for (int s = 0; s < 8; ++s) {
            const float4 a4 = pA[s * 4 + jg], b4 = pB[s * 4 + jg], c4 = pC[s * 4 + jg];
            f32x4 ci;
            ci[0] = fmaf(ph0, a4.x, fmaf(ph1, b4.x, c4.x));
            ci[1] = fmaf(ph0, a4.y, fmaf(ph1, b4.y, c4.y));
            ci[2] = fmaf(ph0, a4.z, fmaf(ph1, b4.z, c4.z));
            ci[3] = fmaf(ph0, a4.w, fmaf(ph1, b4.w, c4.w));
            ci = __builtin_amdgcn_mfma_f32_16x16x32_bf16(w3lds[s * 128 + l],      fa0[nn], ci, 0, 0, 0);
            ci = __builtin_amdgcn_mfma_f32_16x16x32_bf16(w3lds[s * 128 + 64 + l], fa1[nn], ci, 0, 0, 0);
            *(float4*)(ob + 16 * s + jg * 4) =
                make_float4(ci[0] * wsm[0], ci[1] * wsm[1], ci[2] * wsm[2], ci[3] * wsm[3]);
        }
    }
}

extern "C" void kernel_launch(void* const* d_in, const int* in_sizes, int n_in,
                              void* d_out, int out_size, void* d_ws, size_t ws_size,
                              hipStream_t stream)
{
    const float* pts  = (const float*)d_in[0];
    const float* feat = (const float*)d_in[1];
    const float* W1   = (const float*)d_in[2];
    const float* b1   = (const float*)d_in[3];
    const float* Wb   = (const float*)d_in[4];
    const float* bb   = (const float*)d_in[5];
    const float* Wp1  = (const float*)d_in[6];
    const float* gp   = (const float*)d_in[7];
    const float* bp   = (const float*)d_in[8];
    const float* Wp2  = (const float*)d_in[9];
    const float* bp2  = (const float*)d_in[10];
    const float* W2a  = (const float*)d_in[11];
    const float* g2a  = (const float*)d_in[12];
    const float* b2a  = (const float*)d_in[13];
    const float* W2b  = (const float*)d_in[14];
    const float* g2b  = (const float*)d_in[15];
    const float* b2b  = (const float*)d_in[16];
    const float* W2c  = (const float*)d_in[17];
    const float* b2c  = (const float*)d_in[18];
    const float* W3   = (const float*)d_in[19];
    const float* b3   = (const float*)d_in[20];

    float* out       = (float*)d_out;
    float* out_trans = out + (size_t)NK * COUT;
    float* out_idx   = out_trans + (size_t)NK * 2;
    float* ws        = (float*)d_ws;

    hipMemsetAsync(ws, 0, 256 * sizeof(float), stream);
    k_pre<<<512, 256, 0, stream>>>(pts, Wp1, ws);
    k_stage1<<<2048, 256, 0, stream>>>(pts, feat, W1, b1, Wb, bb, Wp1, Wp2, bp2,
                                       gp, bp, W2a, out_trans, out_idx, ws);
    k_red2<<<8, 256, 0, stream>>>(ws);
    k_stage3<<<2048, 256, 0, stream>>>(g2a, b2a, W2b, ws);
    k_stage4<<<2048, 256, 0, stream>>>(feat, Wp1, Wp2, bp2, W2c, b2c, W3, b3,
                                       gp, bp, g2b, b2b, out_trans, ws, out);
}